// Round 4
// baseline (3147.065 us; speedup 1.0000x reference)
//
#include <hip/hip_runtime.h>

#define NF 16384
#define NB 4096
#define EF 262144
#define EB 65536
#define FBLK 1024   // EF/256
#define BBLK 256    // EB/256

__device__ __forceinline__ int cell_bsearch(const int* cs, int i) {
  int cell = 0;
#pragma unroll
  for (int b = 32; b >= 1; b >>= 1)
    if (cell + b <= 63 && cs[cell + b] <= i) cell += b;
  return cell;
}

// ---------------------------------------------------------------------------
// K1: per-edge tent-basis cells/weights + per-block cell histogram.
// ---------------------------------------------------------------------------
__global__ void __launch_bounds__(256) basis_hist_kernel(
    const float* __restrict__ posT, const float* __restrict__ posS,
    const int* __restrict__ tgt, const int* __restrict__ src,
    const float* __restrict__ supportp, float sign,
    uchar4* __restrict__ cells, float4* __restrict__ wts, int* __restrict__ hist) {
  __shared__ int lh[64];
  int t = threadIdx.x;
  if (t < 64) lh[t] = 0;
  __syncthreads();
  int e = blockIdx.x * 256 + t;
  float inv_sup = 1.0f / supportp[0];
  int ti = tgt[e], si = src[e];
  const float2* pT2 = (const float2*)posT;
  const float2* pS2 = (const float2*)posS;
  float2 pt = pT2[ti];
  float2 ps = pS2[si];
  // d = sign * (src - tgt) / support; sign=-1 fluid, +1 boundary.
  // IEEE: (-1)*(+0) = -0 preserves reference signed zeros for self-edges.
  float dx = sign * ((ps.x - pt.x) * inv_sup);
  float dy = sign * ((ps.y - pt.y) * inv_sup);
  dx = fminf(fmaxf(dx, -1.f), 1.f);
  dy = fminf(fmaxf(dy, -1.f), 1.f);
  float r = sqrtf(dx * dx + dy * dy + 1e-12f);
  float theta;
  if (dx == 0.0f && dy == 0.0f) {
    float mag = __builtin_signbitf(dx) ? 3.14159265358979323846f : 0.0f;
    theta = __builtin_signbitf(dy) ? -mag : mag;
  } else {
    theta = atan2f(dy, dx);
  }
  float u = 2.f * r - 1.f;
  float v = theta * (1.f / 3.14159265358979323846f);
  float tu = (u + 1.f) * 3.5f;
  float tv = (v + 1.f) * 3.5f;
  int iu = min(max((int)floorf(tu), 0), 6);
  int iv = min(max((int)floorf(tv), 0), 6);
  float wu0 = fmaxf(0.f, 1.f - fabsf(tu - (float)iu));
  float wu1 = fmaxf(0.f, 1.f - fabsf(tu - (float)(iu + 1)));
  float wv0 = fmaxf(0.f, 1.f - fabsf(tv - (float)iv));
  float wv1 = fmaxf(0.f, 1.f - fabsf(tv - (float)(iv + 1)));
  int c00 = iu * 8 + iv;
  cells[e] = make_uchar4((unsigned char)c00, (unsigned char)(c00 + 1),
                         (unsigned char)(c00 + 8), (unsigned char)(c00 + 9));
  wts[e] = make_float4(wu0 * wv0, wu0 * wv1, wu1 * wv0, wu1 * wv1);
  atomicAdd(&lh[c00], 1);
  atomicAdd(&lh[c00 + 1], 1);
  atomicAdd(&lh[c00 + 8], 1);
  atomicAdd(&lh[c00 + 9], 1);
  __syncthreads();
  if (t < 64) hist[blockIdx.x * 64 + t] = lh[t];
}

// ---------------------------------------------------------------------------
// Parallel cell scans (replaces serial single-wave scan_kernel).
// ---------------------------------------------------------------------------
__global__ void __launch_bounds__(256) cell_totals(const int* __restrict__ hist,
                                                   int nblocks, int* __restrict__ totals) {
  __shared__ int red[256];
  int c = blockIdx.x, t = threadIdx.x;
  int sum = 0;
  for (int b = t; b < nblocks; b += 256) sum += hist[b * 64 + c];
  red[t] = sum;
  __syncthreads();
  for (int s = 128; s > 0; s >>= 1) {
    if (t < s) red[t] += red[t + s];
    __syncthreads();
  }
  if (t == 0) totals[c] = red[0];
}

__global__ void cell_start_scan(const int* __restrict__ totals, int* __restrict__ cell_start) {
  int c = threadIdx.x;  // one wave
  int v = totals[c], s = v;
  for (int off = 1; off < 64; off <<= 1) {
    int o = __shfl_up(s, off, 64);
    if (c >= off) s += o;
  }
  cell_start[c] = s - v;
  if (c == 63) cell_start[64] = s;
}

__global__ void __launch_bounds__(256) blockbase_scan(
    const int* __restrict__ hist, int nblocks, const int* __restrict__ cell_start,
    int* __restrict__ blockbase) {
  int c = blockIdx.x;
  int t = threadIdx.x;
  int lane = t & 63, wv = t >> 6;
  __shared__ int wt[4];
  __shared__ int carry;
  if (t == 0) carry = cell_start[c];
  __syncthreads();
  for (int base = 0; base < nblocks; base += 256) {
    int b = base + t;
    int v = (b < nblocks) ? hist[b * 64 + c] : 0;
    int incl = v;
    for (int off2 = 1; off2 < 64; off2 <<= 1) {
      int o = __shfl_up(incl, off2, 64);
      if (lane >= off2) incl += o;
    }
    if (lane == 63) wt[wv] = incl;
    __syncthreads();
    int wbase = 0;
    for (int k = 0; k < wv; k++) wbase += wt[k];
    int excl = carry + wbase + incl - v;
    if (b < nblocks) blockbase[b * 64 + c] = excl;
    __syncthreads();
    if (t == 0) carry += wt[0] + wt[1] + wt[2] + wt[3];
    __syncthreads();
  }
}

// ---------------------------------------------------------------------------
// K3: scatter into cell-sorted order; writes inverse perm + sorted w/src.
// ---------------------------------------------------------------------------
__global__ void __launch_bounds__(256) scatter_kernel(
    const uchar4* __restrict__ cells, const float4* __restrict__ wts,
    const int* __restrict__ src_idx, const int* __restrict__ blockbase,
    int* __restrict__ inst_pos, float* __restrict__ wsorted, int* __restrict__ srcsorted) {
  __shared__ int cur[64];
  int t = threadIdx.x;
  if (t < 64) cur[t] = blockbase[blockIdx.x * 64 + t];
  __syncthreads();
  int e = blockIdx.x * 256 + t;
  uchar4 c4 = cells[e];
  float4 w4 = wts[e];
  int sr = src_idx[e];
  int p;
  p = atomicAdd(&cur[c4.x], 1); inst_pos[e * 4 + 0] = p; wsorted[p] = w4.x; srcsorted[p] = sr;
  p = atomicAdd(&cur[c4.y], 1); inst_pos[e * 4 + 1] = p; wsorted[p] = w4.y; srcsorted[p] = sr;
  p = atomicAdd(&cur[c4.z], 1); inst_pos[e * 4 + 2] = p; wsorted[p] = w4.z; srcsorted[p] = sr;
  p = atomicAdd(&cur[c4.w], 1); inst_pos[e * 4 + 3] = p; wsorted[p] = w4.w; srcsorted[p] = sr;
}

// ---------------------------------------------------------------------------
// Target CSR build.
// ---------------------------------------------------------------------------
__global__ void __launch_bounds__(256) tgt_hist(const int* __restrict__ tgt, int n,
                                                int* __restrict__ hist) {
  int e = blockIdx.x * 256 + threadIdx.x;
  if (e < n) atomicAdd(hist + tgt[e], 1);
}

__global__ void __launch_bounds__(1024) csr_scan(const int* __restrict__ hist,
                                                 int* __restrict__ start,
                                                 int* __restrict__ cursor) {
  __shared__ int wtot[16];
  int t = threadIdx.x;
  int lane = t & 63, wv = t >> 6;
  int base = t * 16;
  int vals[16];
  int s = 0;
#pragma unroll
  for (int k = 0; k < 16; k++) { vals[k] = hist[base + k]; s += vals[k]; }
  int ss = s;
  for (int off = 1; off < 64; off <<= 1) {
    int o = __shfl_up(ss, off, 64);
    if (lane >= off) ss += o;
  }
  if (lane == 63) wtot[wv] = ss;
  __syncthreads();
  if (t < 16) {
    int v = wtot[t];
    int vv = v;
    for (int off = 1; off < 16; off <<= 1) {
      int o = __shfl_up(vv, off, 64);
      if (t >= off) vv += o;
    }
    wtot[t] = vv - v;
  }
  __syncthreads();
  int run = ss - s + wtot[wv];
#pragma unroll
  for (int k = 0; k < 16; k++) { start[base + k] = run; cursor[base + k] = run; run += vals[k]; }
  if (t == 1023) start[16384] = run;
}

__global__ void __launch_bounds__(256) tgt_scatter(const int* __restrict__ tgt, int n,
                                                   int* __restrict__ cursor,
                                                   int* __restrict__ edges) {
  int e = blockIdx.x * 256 + threadIdx.x;
  if (e < n) { int p = atomicAdd(cursor + tgt[e], 1); edges[p] = e; }
}

// pos4[idx] = the 4 sorted instance positions of edge edges[idx] (CSR order).
__global__ void __launch_bounds__(256) build_pos4(const int* __restrict__ edges,
                                                  const int* __restrict__ instpos, int n,
                                                  int4* __restrict__ pos4) {
  int idx = blockIdx.x * 256 + threadIdx.x;
  if (idx < n) pos4[idx] = *(const int4*)(instpos + 4 * edges[idx]);
}

// ---------------------------------------------------------------------------
// Phase A, cout=64. (256,2): Wreg must stay register-resident. 2-inst unroll.
// ---------------------------------------------------------------------------
template <int CIN>
__global__ void __launch_bounds__(256, 2) msg_conv64(
    const int* __restrict__ srcsorted, const float* __restrict__ wsorted,
    const int* __restrict__ cell_start, const float* __restrict__ x,
    const float* __restrict__ W, float* __restrict__ msg, int p0, int p1) {
  __shared__ int cs[65];
  if (threadIdx.x < 65) cs[threadIdx.x] = cell_start[threadIdx.x];
  __syncthreads();
  int lane = threadIdx.x & 63;
  int gw = blockIdx.x * 4 + (threadIdx.x >> 6);
  int nw = gridDim.x * 4;
  int total = p1 - p0;
  int per = (total + nw - 1) / nw;
  int i0 = p0 + gw * per;
  int i1 = min(i0 + per, p1);
  if (i0 >= i1) return;
  int cell = cell_bsearch(cs, i0);
  float Wreg[CIN];
  {
    const float* Wc = W + cell * (CIN * 64) + lane;
#pragma unroll
    for (int ci = 0; ci < CIN; ci++) Wreg[ci] = Wc[ci * 64];
  }
  int i = i0;
  while (i < i1) {
    if (i >= cs[cell + 1]) {
      do { cell++; } while (i >= cs[cell + 1]);
      const float* Wc = W + cell * (CIN * 64) + lane;
#pragma unroll
      for (int ci = 0; ci < CIN; ci++) Wreg[ci] = Wc[ci * 64];
    }
    int lim = min(i1, cs[cell + 1]);
    for (; i + 1 < lim; i += 2) {
      int sr0 = srcsorted[i], sr1 = srcsorted[i + 1];
      float w0 = wsorted[i], w1 = wsorted[i + 1];
      const float4* __restrict__ xr0 = (const float4*)(x + (size_t)sr0 * CIN);
      const float4* __restrict__ xr1 = (const float4*)(x + (size_t)sr1 * CIN);
      float a0 = 0.f, a1 = 0.f, a2 = 0.f, a3 = 0.f;
      float b0 = 0.f, b1 = 0.f, b2 = 0.f, b3 = 0.f;
#pragma unroll
      for (int q = 0; q < CIN / 4; q++) {
        float4 u = xr0[q];
        float4 v = xr1[q];
        a0 = fmaf(u.x, Wreg[4 * q + 0], a0); b0 = fmaf(v.x, Wreg[4 * q + 0], b0);
        a1 = fmaf(u.y, Wreg[4 * q + 1], a1); b1 = fmaf(v.y, Wreg[4 * q + 1], b1);
        a2 = fmaf(u.z, Wreg[4 * q + 2], a2); b2 = fmaf(v.z, Wreg[4 * q + 2], b2);
        a3 = fmaf(u.w, Wreg[4 * q + 3], a3); b3 = fmaf(v.w, Wreg[4 * q + 3], b3);
      }
      msg[(size_t)(i - p0) * 64 + lane] = ((a0 + a1) + (a2 + a3)) * w0;
      msg[(size_t)(i + 1 - p0) * 64 + lane] = ((b0 + b1) + (b2 + b3)) * w1;
    }
    if (i < lim) {
      int sr0 = srcsorted[i];
      float w0 = wsorted[i];
      const float4* __restrict__ xr0 = (const float4*)(x + (size_t)sr0 * CIN);
      float a0 = 0.f, a1 = 0.f, a2 = 0.f, a3 = 0.f;
#pragma unroll
      for (int q = 0; q < CIN / 4; q++) {
        float4 u = xr0[q];
        a0 = fmaf(u.x, Wreg[4 * q + 0], a0);
        a1 = fmaf(u.y, Wreg[4 * q + 1], a1);
        a2 = fmaf(u.z, Wreg[4 * q + 2], a2);
        a3 = fmaf(u.w, Wreg[4 * q + 3], a3);
      }
      msg[(size_t)(i - p0) * 64 + lane] = ((a0 + a1) + (a2 + a3)) * w0;
      i++;
    }
  }
}

// ---------------------------------------------------------------------------
// Phase A, cin=4 cout=32 (W0/W1): 8 instances (4 half-wave pairs) per iter.
// ---------------------------------------------------------------------------
__global__ void __launch_bounds__(256, 2) msg_conv32(
    const int* __restrict__ srcsorted, const float* __restrict__ wsorted,
    const int* __restrict__ cell_start, const float* __restrict__ x,
    const float* __restrict__ W /*[64][4][32]*/, float* __restrict__ msg, int p0, int p1) {
  __shared__ int cs[65];
  if (threadIdx.x < 65) cs[threadIdx.x] = cell_start[threadIdx.x];
  __syncthreads();
  int lane = threadIdx.x & 63;
  int co = lane & 31;
  int half = lane >> 5;
  int gw = blockIdx.x * 4 + (threadIdx.x >> 6);
  int nw = gridDim.x * 4;
  int pairs = (p1 - p0) >> 1;
  int perp = ((pairs + nw - 1) / nw + 3) & ~3;  // pairs per wave, multiple of 4
  int k0 = p0 + gw * perp * 2;
  int k1 = min(k0 + perp * 2, p1);
  if (k0 >= k1) return;
  for (int k = k0; k < k1; k += 8) {
#pragma unroll
    for (int j = 0; j < 4; j++) {
      int pj = k + 2 * j;
      bool act = pj < k1;
      int ii = act ? (pj + half) : (p1 - 1);
      int cell = cell_bsearch(cs, ii);
      int sr = srcsorted[ii];
      float wv_ = wsorted[ii];
      const float* Wc = W + cell * 128 + co;
      float4 xv = *(const float4*)(x + (size_t)sr * 4);
      float acc = xv.x * Wc[0] + xv.y * Wc[32] + xv.z * Wc[64] + xv.w * Wc[96];
      if (act) msg[(size_t)(pj - p0) * 32 + lane] = acc * wv_;
    }
  }
}

// ---------------------------------------------------------------------------
// Phase A, cin=64 cout=2 (W4): 8 instances per wave-iter; lane = (grp=inst, sub=cin/8).
// ---------------------------------------------------------------------------
__global__ void __launch_bounds__(256, 2) msg_conv2(
    const int* __restrict__ srcsorted, const float* __restrict__ wsorted,
    const int* __restrict__ cell_start, const float* __restrict__ x,
    const float* __restrict__ W /*[64][64][2]*/, float2* __restrict__ msg, int p0, int p1) {
  __shared__ int cs[65];
  if (threadIdx.x < 65) cs[threadIdx.x] = cell_start[threadIdx.x];
  __syncthreads();
  int lane = threadIdx.x & 63;
  int sub = lane & 7;   // cin octet
  int grp = lane >> 3;  // instance in batch of 8
  int gw = blockIdx.x * 4 + (threadIdx.x >> 6);
  int nw = gridDim.x * 4;
  int total = p1 - p0;
  int per = (((total + nw - 1) / nw) + 7) & ~7;
  int i0 = p0 + gw * per;
  int i1 = min(i0 + per, p1);
  if (i0 >= i1) return;
  for (int base = i0; base < i1; base += 8) {
    int i = base + grp;
    bool act = i < i1;
    int ii = act ? i : (p1 - 1);
    int cell = cell_bsearch(cs, ii);
    int sr = srcsorted[ii];
    float w = wsorted[ii];
    const float4* __restrict__ xr = (const float4*)(x + (size_t)sr * 64 + sub * 8);
    float4 x0 = xr[0], x1 = xr[1];
    const float4* __restrict__ wr = (const float4*)(W + cell * 128 + sub * 16);
    float4 wa = wr[0], wb = wr[1], wc4 = wr[2], wd = wr[3];
    float m0 = x0.x * wa.x + x0.y * wa.z + x0.z * wb.x + x0.w * wb.z +
               x1.x * wc4.x + x1.y * wc4.z + x1.z * wd.x + x1.w * wd.z;
    float m1 = x0.x * wa.y + x0.y * wa.w + x0.z * wb.y + x0.w * wb.w +
               x1.x * wc4.y + x1.y * wc4.w + x1.z * wd.y + x1.w * wd.w;
#pragma unroll
    for (int off = 1; off < 8; off <<= 1) {
      m0 += __shfl_xor(m0, off, 64);
      m1 += __shfl_xor(m1, off, 64);
    }
    if (sub == 0 && act) msg[i - p0] = make_float2(m0 * w, m1 * w);
  }
}

// ---------------------------------------------------------------------------
// Phase B stage 1: fluid msgs (cols 32..63) + bdy msgs (64..95) + lin (0..31).
// ---------------------------------------------------------------------------
__global__ void __launch_bounds__(256, 4) b1_stage1(
    const float* __restrict__ ff, const float* __restrict__ fc0,
    const int* __restrict__ ftstart, const int4* __restrict__ fpos4,
    const float* __restrict__ msgF,
    const int* __restrict__ btstart, const int4* __restrict__ bpos4,
    const float* __restrict__ msgB,
    float* __restrict__ ans0, int p0, int p1, int init, int fin) {
  int lane = threadIdx.x & 63;
  int t = blockIdx.x * 4 + (threadIdx.x >> 6);
  int co = lane & 31;
  float f = 0.f;
  int s = ftstart[t], e1 = ftstart[t + 1];
  for (int idx = s; idx < e1; idx++) {
    int4 p4 = fpos4[idx];
    int pa = (lane < 32) ? p4.x : p4.y;
    int pb = (lane < 32) ? p4.z : p4.w;
    if (pa >= p0 && pa < p1) f += msgF[(size_t)(pa - p0) * 32 + co];
    if (pb >= p0 && pb < p1) f += msgF[(size_t)(pb - p0) * 32 + co];
  }
  f += __shfl_xor(f, 32, 64);
  if (!init) f += ans0[t * 96 + 32 + co];
  if (fin) f = fmaxf(f, 0.f);
  if (lane < 32) ans0[t * 96 + 32 + lane] = f;
  if (init) {
    float b = 0.f;
    int bs = btstart[t], be = btstart[t + 1];
    for (int idx = bs; idx < be; idx++) {
      int4 p4 = bpos4[idx];
      int pa = (lane < 32) ? p4.x : p4.y;
      int pb = (lane < 32) ? p4.z : p4.w;
      b += msgB[(size_t)pa * 32 + co];
      b += msgB[(size_t)pb * 32 + co];
    }
    b += __shfl_xor(b, 32, 64);
    if (lane >= 32) ans0[t * 96 + 64 + co] = fmaxf(b, 0.f);
    if (lane < 32) {
      float4 fv = *(const float4*)(ff + t * 4);
      float a = fv.x * fc0[lane] + fv.y * fc0[32 + lane] + fv.z * fc0[64 + lane] +
                fv.w * fc0[96 + lane];
      ans0[t * 96 + lane] = fmaxf(a, 0.f);
    }
  }
}

// ---------------------------------------------------------------------------
// Phase B stages 2/3: dest = relu(conv_sum + xin@fc (+resid)); pos4 stream.
// ---------------------------------------------------------------------------
template <int CIN, int RESID>
__global__ void __launch_bounds__(256, 4) b23(
    const float* __restrict__ xin, const float* __restrict__ fc,
    const int* __restrict__ ftstart, const int4* __restrict__ fpos4,
    const float* __restrict__ msg, const float* __restrict__ resid,
    float* __restrict__ dest, int p0, int p1, int init, int fin) {
  int lane = threadIdx.x & 63;
  int t = blockIdx.x * 4 + (threadIdx.x >> 6);
  float acc;
  if (init) {
    acc = RESID ? resid[(size_t)t * 64 + lane] : 0.f;
    const float4* __restrict__ xr = (const float4*)(xin + (size_t)t * CIN);
#pragma unroll
    for (int q = 0; q < CIN / 4; q++) {
      float4 xv = xr[q];
      acc = fmaf(xv.x, fc[(4 * q + 0) * 64 + lane], acc);
      acc = fmaf(xv.y, fc[(4 * q + 1) * 64 + lane], acc);
      acc = fmaf(xv.z, fc[(4 * q + 2) * 64 + lane], acc);
      acc = fmaf(xv.w, fc[(4 * q + 3) * 64 + lane], acc);
    }
  } else {
    acc = dest[(size_t)t * 64 + lane];
  }
  int s = ftstart[t], e1 = ftstart[t + 1];
  int idx = s;
  for (; idx + 1 < e1; idx += 2) {
    int4 pA = fpos4[idx];
    int4 pB = fpos4[idx + 1];
    if (pA.x >= p0 && pA.x < p1) acc += msg[(size_t)(pA.x - p0) * 64 + lane];
    if (pA.y >= p0 && pA.y < p1) acc += msg[(size_t)(pA.y - p0) * 64 + lane];
    if (pA.z >= p0 && pA.z < p1) acc += msg[(size_t)(pA.z - p0) * 64 + lane];
    if (pA.w >= p0 && pA.w < p1) acc += msg[(size_t)(pA.w - p0) * 64 + lane];
    if (pB.x >= p0 && pB.x < p1) acc += msg[(size_t)(pB.x - p0) * 64 + lane];
    if (pB.y >= p0 && pB.y < p1) acc += msg[(size_t)(pB.y - p0) * 64 + lane];
    if (pB.z >= p0 && pB.z < p1) acc += msg[(size_t)(pB.z - p0) * 64 + lane];
    if (pB.w >= p0 && pB.w < p1) acc += msg[(size_t)(pB.w - p0) * 64 + lane];
  }
  if (idx < e1) {
    int4 pA = fpos4[idx];
    if (pA.x >= p0 && pA.x < p1) acc += msg[(size_t)(pA.x - p0) * 64 + lane];
    if (pA.y >= p0 && pA.y < p1) acc += msg[(size_t)(pA.y - p0) * 64 + lane];
    if (pA.z >= p0 && pA.z < p1) acc += msg[(size_t)(pA.z - p0) * 64 + lane];
    if (pA.w >= p0 && pA.w < p1) acc += msg[(size_t)(pA.w - p0) * 64 + lane];
  }
  dest[(size_t)t * 64 + lane] = fin ? fmaxf(acc, 0.f) : acc;
}

// ---------------------------------------------------------------------------
// Phase B stage 4: out[t] = sum msg2 + ans2@fc3. Flattened pos stream.
// ---------------------------------------------------------------------------
__global__ void __launch_bounds__(256, 4) b4_stage4(
    const float* __restrict__ ans2, const float* __restrict__ fc3,
    const int* __restrict__ ftstart, const int* __restrict__ fposflat,
    const float2* __restrict__ msg2, float* __restrict__ partial,
    float* __restrict__ outp, int p0, int p1, int init, int fin) {
  int lane = threadIdx.x & 63;
  int t = blockIdx.x * 4 + (threadIdx.x >> 6);
  int s4 = ftstart[t] * 4, e4 = ftstart[t + 1] * 4;
  float m0 = 0.f, m1 = 0.f;
  for (int idx = s4 + lane; idx < e4; idx += 64) {
    int p = fposflat[idx];
    if (p >= p0 && p < p1) {
      float2 mm = msg2[p - p0];
      m0 += mm.x;
      m1 += mm.y;
    }
  }
  if (init) {
    float a = ans2[(size_t)t * 64 + lane];
    m0 += a * fc3[lane * 2 + 0];
    m1 += a * fc3[lane * 2 + 1];
  }
#pragma unroll
  for (int off = 32; off > 0; off >>= 1) {
    m0 += __shfl_xor(m0, off, 64);
    m1 += __shfl_xor(m1, off, 64);
  }
  if (lane == 0) {
    if (!init) { m0 += partial[t * 2]; m1 += partial[t * 2 + 1]; }
    if (fin) { outp[t * 2] = m0; outp[t * 2 + 1] = m1; }
    else { partial[t * 2] = m0; partial[t * 2 + 1] = m1; }
  }
}

// ---------------------------------------------------------------------------
extern "C" void kernel_launch(void* const* d_in, const int* in_sizes, int n_in,
                              void* d_out, int out_size, void* d_ws, size_t ws_size,
                              hipStream_t stream) {
  const float* fp  = (const float*)d_in[0];
  const float* bp  = (const float*)d_in[1];
  const float* ff  = (const float*)d_in[2];
  const float* bfe = (const float*)d_in[3];
  const float* sup = (const float*)d_in[4];
  const int* fi  = (const int*)d_in[5];
  const int* fj  = (const int*)d_in[6];
  const int* bfi = (const int*)d_in[7];
  const int* bb  = (const int*)d_in[8];
  const float* W0 = (const float*)d_in[9];
  const float* W1 = (const float*)d_in[10];
  const float* W2 = (const float*)d_in[11];
  const float* W3 = (const float*)d_in[12];
  const float* W4 = (const float*)d_in[13];
  const float* fc0 = (const float*)d_in[14];
  const float* fc1 = (const float*)d_in[15];
  const float* fc2 = (const float*)d_in[16];
  const float* fc3 = (const float*)d_in[17];
  float* out = (float*)d_out;

  const int TOTF = EF * 4;
  const int TOTB = EB * 4;

  char* w = (char*)d_ws;
  size_t off = 0;
  auto alloc = [&](size_t bytes) {
    char* p = w + off;
    off += (bytes + 255) & ~size_t(255);
    return p;
  };
  float* ans0   = (float*)alloc((size_t)NF * 96 * 4);
  float* ans1   = (float*)alloc((size_t)NF * 64 * 4);
  float* ans2   = (float*)alloc((size_t)NF * 64 * 4);
  float* outpre = (float*)alloc((size_t)NF * 2 * 4);
  uchar4* fcells = (uchar4*)alloc((size_t)EF * 4);
  float4* fwts   = (float4*)alloc((size_t)EF * 16);
  uchar4* bcells = (uchar4*)alloc((size_t)EB * 4);
  float4* bwts   = (float4*)alloc((size_t)EB * 16);
  int* fhist = (int*)alloc((size_t)FBLK * 64 * 4);
  int* fbase = (int*)alloc((size_t)FBLK * 64 * 4);
  int* bhist = (int*)alloc((size_t)BBLK * 64 * 4);
  int* bbase = (int*)alloc((size_t)BBLK * 64 * 4);
  int* fcs  = (int*)alloc(65 * 4);
  int* bcs  = (int*)alloc(65 * 4);
  int* ftot = (int*)alloc(64 * 4);
  int* btot = (int*)alloc(64 * 4);
  int* finstpos = (int*)alloc((size_t)TOTF * 4);
  int* fsrc     = (int*)alloc((size_t)TOTF * 4);
  float* fw     = (float*)alloc((size_t)TOTF * 4);
  int* binstpos = (int*)alloc((size_t)TOTB * 4);
  int* bsrc     = (int*)alloc((size_t)TOTB * 4);
  float* bw     = (float*)alloc((size_t)TOTB * 4);
  int* fthist  = (int*)alloc((size_t)NF * 4);
  int* ftstart = (int*)alloc((size_t)(NF + 1) * 4);
  int* ftcur   = (int*)alloc((size_t)NF * 4);
  int* ftedges = (int*)alloc((size_t)EF * 4);
  int* bthist  = (int*)alloc((size_t)NF * 4);
  int* btstart = (int*)alloc((size_t)(NF + 1) * 4);
  int* btcur   = (int*)alloc((size_t)NF * 4);
  int* btedges = (int*)alloc((size_t)EB * 4);
  int4* fpos4  = (int4*)alloc((size_t)EF * 16);
  int4* bpos4  = (int4*)alloc((size_t)EB * 16);
  float* msgB  = (float*)alloc((size_t)TOTB * 32 * 4);
  float* msgF = (float*)(w + off);
  size_t M = (ws_size > off) ? (ws_size - off) : 0;
  long long Hcap = (long long)(M / 256) & ~511LL;
  int H = (Hcap < 512) ? 512 : (Hcap > TOTF ? TOTF : (int)Hcap);
  int S = (TOTF + H - 1) / H;

  hipMemsetAsync(fthist, 0, (size_t)NF * 4, stream);
  hipMemsetAsync(bthist, 0, (size_t)NF * 4, stream);

  basis_hist_kernel<<<FBLK, 256, 0, stream>>>(fp, fp, fi, fj, sup, -1.f, fcells, fwts, fhist);
  basis_hist_kernel<<<BBLK, 256, 0, stream>>>(fp, bp, bfi, bb, sup, 1.f, bcells, bwts, bhist);
  cell_totals<<<64, 256, 0, stream>>>(fhist, FBLK, ftot);
  cell_totals<<<64, 256, 0, stream>>>(bhist, BBLK, btot);
  cell_start_scan<<<1, 64, 0, stream>>>(ftot, fcs);
  cell_start_scan<<<1, 64, 0, stream>>>(btot, bcs);
  blockbase_scan<<<64, 256, 0, stream>>>(fhist, FBLK, fcs, fbase);
  blockbase_scan<<<64, 256, 0, stream>>>(bhist, BBLK, bcs, bbase);
  scatter_kernel<<<FBLK, 256, 0, stream>>>(fcells, fwts, fj, fbase, finstpos, fw, fsrc);
  scatter_kernel<<<BBLK, 256, 0, stream>>>(bcells, bwts, bb, bbase, binstpos, bw, bsrc);

  tgt_hist<<<FBLK, 256, 0, stream>>>(fi, EF, fthist);
  tgt_hist<<<BBLK, 256, 0, stream>>>(bfi, EB, bthist);
  csr_scan<<<1, 1024, 0, stream>>>(fthist, ftstart, ftcur);
  csr_scan<<<1, 1024, 0, stream>>>(bthist, btstart, btcur);
  tgt_scatter<<<FBLK, 256, 0, stream>>>(fi, EF, ftcur, ftedges);
  tgt_scatter<<<BBLK, 256, 0, stream>>>(bfi, EB, btcur, btedges);
  build_pos4<<<FBLK, 256, 0, stream>>>(ftedges, finstpos, EF, fpos4);
  build_pos4<<<BBLK, 256, 0, stream>>>(btedges, binstpos, EB, bpos4);

  // Stage 1
  msg_conv32<<<512, 256, 0, stream>>>(bsrc, bw, bcs, bfe, W1, msgB, 0, TOTB);
  for (int c = 0; c < S; c++) {
    int q0 = c * H, q1 = min(TOTF, (c + 1) * H);
    msg_conv32<<<2048, 256, 0, stream>>>(fsrc, fw, fcs, ff, W0, msgF, q0, q1);
    b1_stage1<<<NF / 4, 256, 0, stream>>>(ff, fc0, ftstart, fpos4, msgF,
                                          btstart, bpos4, msgB, ans0,
                                          q0, q1, c == 0, c == S - 1);
  }
  // Stage 2
  for (int c = 0; c < S; c++) {
    int q0 = c * H, q1 = min(TOTF, (c + 1) * H);
    msg_conv64<96><<<2048, 256, 0, stream>>>(fsrc, fw, fcs, ans0, W2, msgF, q0, q1);
    b23<96, 0><<<NF / 4, 256, 0, stream>>>(ans0, fc1, ftstart, fpos4, msgF,
                                           nullptr, ans1, q0, q1, c == 0, c == S - 1);
  }
  // Stage 3
  for (int c = 0; c < S; c++) {
    int q0 = c * H, q1 = min(TOTF, (c + 1) * H);
    msg_conv64<64><<<2048, 256, 0, stream>>>(fsrc, fw, fcs, ans1, W3, msgF, q0, q1);
    b23<64, 1><<<NF / 4, 256, 0, stream>>>(ans1, fc2, ftstart, fpos4, msgF,
                                           ans1, ans2, q0, q1, c == 0, c == S - 1);
  }
  // Stage 4
  for (int c = 0; c < S; c++) {
    int q0 = c * H, q1 = min(TOTF, (c + 1) * H);
    msg_conv2<<<2048, 256, 0, stream>>>(fsrc, fw, fcs, ans2, W4, (float2*)msgF, q0, q1);
    b4_stage4<<<NF / 4, 256, 0, stream>>>(ans2, fc3, ftstart, (const int*)fpos4,
                                          (const float2*)msgF, outpre, out,
                                          q0, q1, c == 0, c == S - 1);
  }
}

// Round 5
// 658.265 us; speedup vs baseline: 4.7809x; 4.7809x over previous
//
#include <hip/hip_runtime.h>

#define NF 16384
#define NB 4096
#define EF 262144
#define EB 65536
#define FBLK 1024   // EF/256
#define BBLK 256    // EB/256

typedef __attribute__((ext_vector_type(8))) short bf16x8;
typedef __attribute__((ext_vector_type(4))) float f32x4;

__device__ __forceinline__ short f2b(float f) {
  unsigned u = __float_as_uint(f);
  u += 0x7fff + ((u >> 16) & 1);   // RNE
  return (short)(u >> 16);
}
__device__ __forceinline__ float b2f(short s) {
  return __uint_as_float(((unsigned)(unsigned short)s) << 16);
}

// ---------------------------------------------------------------------------
// Per-edge tent-basis cells + bilinear weights (no sort needed anymore).
// ---------------------------------------------------------------------------
__global__ void __launch_bounds__(256) basis_kernel(
    const float* __restrict__ posT, const float* __restrict__ posS,
    const int* __restrict__ tgt, const int* __restrict__ src,
    const float* __restrict__ supportp, float sign,
    uchar4* __restrict__ cells, float4* __restrict__ wts) {
  int e = blockIdx.x * 256 + threadIdx.x;
  float inv_sup = 1.0f / supportp[0];
  int ti = tgt[e], si = src[e];
  const float2* pT2 = (const float2*)posT;
  const float2* pS2 = (const float2*)posS;
  float2 pt = pT2[ti];
  float2 ps = pS2[si];
  // d = sign*(src-tgt)/support; sign=-1 fluid, +1 boundary. (-1)*(+0) = -0
  // preserves reference signed zeros for self-edges (atan2(-0,-0) = -pi).
  float dx = sign * ((ps.x - pt.x) * inv_sup);
  float dy = sign * ((ps.y - pt.y) * inv_sup);
  dx = fminf(fmaxf(dx, -1.f), 1.f);
  dy = fminf(fmaxf(dy, -1.f), 1.f);
  float r = sqrtf(dx * dx + dy * dy + 1e-12f);
  float theta;
  if (dx == 0.0f && dy == 0.0f) {
    float mag = __builtin_signbitf(dx) ? 3.14159265358979323846f : 0.0f;
    theta = __builtin_signbitf(dy) ? -mag : mag;
  } else {
    theta = atan2f(dy, dx);
  }
  float u = 2.f * r - 1.f;
  float v = theta * (1.f / 3.14159265358979323846f);
  float tu = (u + 1.f) * 3.5f;
  float tv = (v + 1.f) * 3.5f;
  int iu = min(max((int)floorf(tu), 0), 6);
  int iv = min(max((int)floorf(tv), 0), 6);
  float wu0 = fmaxf(0.f, 1.f - fabsf(tu - (float)iu));
  float wu1 = fmaxf(0.f, 1.f - fabsf(tu - (float)(iu + 1)));
  float wv0 = fmaxf(0.f, 1.f - fabsf(tv - (float)iv));
  float wv1 = fmaxf(0.f, 1.f - fabsf(tv - (float)(iv + 1)));
  int c00 = iu * 8 + iv;
  cells[e] = make_uchar4((unsigned char)c00, (unsigned char)(c00 + 1),
                         (unsigned char)(c00 + 8), (unsigned char)(c00 + 9));
  wts[e] = make_float4(wu0 * wv0, wu0 * wv1, wu1 * wv0, wu1 * wv1);
}

// ---------------------------------------------------------------------------
// Target CSR build (by target node).
// ---------------------------------------------------------------------------
__global__ void __launch_bounds__(256) tgt_hist(const int* __restrict__ tgt, int n,
                                                int* __restrict__ hist) {
  int e = blockIdx.x * 256 + threadIdx.x;
  if (e < n) atomicAdd(hist + tgt[e], 1);
}

__global__ void __launch_bounds__(1024) csr_scan(const int* __restrict__ hist,
                                                 int* __restrict__ start,
                                                 int* __restrict__ cursor) {
  __shared__ int wtot[16];
  int t = threadIdx.x;
  int lane = t & 63, wv = t >> 6;
  int base = t * 16;
  int vals[16];
  int s = 0;
#pragma unroll
  for (int k = 0; k < 16; k++) { vals[k] = hist[base + k]; s += vals[k]; }
  int ss = s;
  for (int off = 1; off < 64; off <<= 1) {
    int o = __shfl_up(ss, off, 64);
    if (lane >= off) ss += o;
  }
  if (lane == 63) wtot[wv] = ss;
  __syncthreads();
  if (t < 16) {
    int v = wtot[t];
    int vv = v;
    for (int off = 1; off < 16; off <<= 1) {
      int o = __shfl_up(vv, off, 64);
      if (t >= off) vv += o;
    }
    wtot[t] = vv - v;
  }
  __syncthreads();
  int run = ss - s + wtot[wv];
#pragma unroll
  for (int k = 0; k < 16; k++) { start[base + k] = run; cursor[base + k] = run; run += vals[k]; }
  if (t == 1023) start[16384] = run;
}

__global__ void __launch_bounds__(256) tgt_scatter(const int* __restrict__ tgt, int n,
                                                   int* __restrict__ cursor,
                                                   int* __restrict__ edges) {
  int e = blockIdx.x * 256 + threadIdx.x;
  if (e < n) { int p = atomicAdd(cursor + tgt[e], 1); edges[p] = e; }
}

// Per-CSR-slot payload: source node, 4 cells, 4 weights (streamed in phase B).
__global__ void __launch_bounds__(256) build_payload(
    const int* __restrict__ edges, const int* __restrict__ srcarr,
    const uchar4* __restrict__ cells, const float4* __restrict__ wts, int n,
    int* __restrict__ esrc, uchar4* __restrict__ ecell, float4* __restrict__ ewt) {
  int idx = blockIdx.x * 256 + threadIdx.x;
  if (idx < n) {
    int e = edges[idx];
    esrc[idx] = srcarr[e];
    ecell[idx] = cells[e];
    ewt[idx] = wts[e];
  }
}

// ---------------------------------------------------------------------------
// Converts: fp32 -> bf16 activations; B^T weight build.
// ---------------------------------------------------------------------------
__global__ void __launch_bounds__(256) cvt_f2b(const float* __restrict__ x,
                                               short* __restrict__ y, int n) {
  int i = blockIdx.x * 256 + threadIdx.x;
  if (i < n) y[i] = f2b(x[i]);
}

// BT[n][k] = bf16(W[cell=n>>6][k][co=n&63]);  n in [0,4096), k in [0,K)
__global__ void __launch_bounds__(256) buildBT(const float* __restrict__ W,
                                               short* __restrict__ BT, int K) {
  int tid = blockIdx.x * 256 + threadIdx.x;
  if (tid >= 4096 * K) return;
  int k = tid % K, n = tid / K;
  BT[tid] = f2b(W[((size_t)(n >> 6) * K + k) * 64 + (n & 63)]);
}

// ---------------------------------------------------------------------------
// Dense MFMA GEMM: C[M][N] = A[M][K] @ B[K][N], bf16 in, fp32 acc, bf16 out.
// B passed transposed: BT[n][k]. Block = 128x128 (4 waves, 2x2 of 64x64).
// No LDS: A/B fragments loaded directly (L2-hot; K<=96).
// Verified layout (m89/m91): A-frag lane holds A[m=lane&15][k=(lane>>4)*8+j];
// B-frag lane holds B[k=(lane>>4)*8+j][n=lane&15]; D elem: col(n)=lane&15,
// row(m)=(lane>>4)*4+reg.
// ---------------------------------------------------------------------------
template <int K>
__global__ void __launch_bounds__(256, 2) gemm_bf16(
    const short* __restrict__ A, const short* __restrict__ BT,
    short* __restrict__ C, int N) {
  int lane = threadIdx.x & 63;
  int w = threadIdx.x >> 6;
  int m0 = blockIdx.x * 128 + (w & 1) * 64;
  int n0 = blockIdx.y * 128 + (w >> 1) * 64;
  int fr = lane & 15;
  int kg = lane >> 4;
  f32x4 acc[4][4] = {};
#pragma unroll
  for (int kc = 0; kc < K; kc += 32) {
    bf16x8 a[4], b[4];
#pragma unroll
    for (int i = 0; i < 4; i++) {
      a[i] = *(const bf16x8*)(A + (size_t)(m0 + i * 16 + fr) * K + kc + kg * 8);
      b[i] = *(const bf16x8*)(BT + (size_t)(n0 + i * 16 + fr) * K + kc + kg * 8);
    }
#pragma unroll
    for (int i = 0; i < 4; i++)
#pragma unroll
      for (int j = 0; j < 4; j++)
        acc[i][j] = __builtin_amdgcn_mfma_f32_16x16x32_bf16(a[i], b[j], acc[i][j], 0, 0, 0);
  }
#pragma unroll
  for (int i = 0; i < 4; i++) {
    int row = m0 + i * 16 + (lane >> 4) * 4;
#pragma unroll
    for (int j = 0; j < 4; j++) {
      int col = n0 + j * 16 + (lane & 15);
#pragma unroll
      for (int r = 0; r < 4; r++)
        C[(size_t)(row + r) * N + col] = f2b(acc[i][j][r]);
    }
  }
}

// ---------------------------------------------------------------------------
// Stage-1 dense conv (K=4, 32 couts/cell): Y[n][cellL*32+co] bf16.
// grid = (M*32/256, CC)
// ---------------------------------------------------------------------------
__global__ void __launch_bounds__(256) conv_k4_c32(
    const float* __restrict__ x, const float* __restrict__ W /*[64][4][32]*/,
    short* __restrict__ Y, int c0, int CC) {
  int t = threadIdx.x;
  int co = t & 31;
  int n = (blockIdx.x * 256 + t) >> 5;
  int cellL = blockIdx.y;
  const float* Wc = W + (c0 + cellL) * 128 + co;
  float4 xv = *(const float4*)(x + (size_t)n * 4);
  float a = xv.x * Wc[0] + xv.y * Wc[32] + xv.z * Wc[64] + xv.w * Wc[96];
  Y[(size_t)n * (CC * 32) + cellL * 32 + co] = f2b(a);
}

// ---------------------------------------------------------------------------
// Stage-4 dense conv (K=64, 2 couts/cell): Y4[n][cellL*2+q] fp32.
// grid = (NF*2/256, CC)
// ---------------------------------------------------------------------------
__global__ void __launch_bounds__(256) conv_k64_c2(
    const float* __restrict__ x, const float* __restrict__ W4 /*[64][64][2]*/,
    float* __restrict__ Y4, int c0, int CC) {
  int t = threadIdx.x;
  int q = t & 1;
  int n = (blockIdx.x * 256 + t) >> 1;
  int cellL = blockIdx.y;
  const float* wr = W4 + (size_t)(c0 + cellL) * 128 + q;
  const float4* xr = (const float4*)(x + (size_t)n * 64);
  float a = 0.f;
#pragma unroll
  for (int k = 0; k < 16; k++) {
    float4 xv = xr[k];
    a += xv.x * wr[(4 * k) * 2] + xv.y * wr[(4 * k + 1) * 2] +
         xv.z * wr[(4 * k + 2) * 2] + xv.w * wr[(4 * k + 3) * 2];
  }
  Y4[(size_t)n * (CC * 2) + cellL * 2 + q] = a;
}

// ---------------------------------------------------------------------------
// Phase B stage 1: fluid conv (cols 32..63) + bdy conv (64..95) + lin (0..31).
// Half-wave handles cells (x,z), other half (y,w); cross-half reduce.
// ---------------------------------------------------------------------------
__global__ void __launch_bounds__(256, 4) b1_stage1(
    const float* __restrict__ ff, const float* __restrict__ fc0,
    const int* __restrict__ ftstart, const int* __restrict__ fsrcP,
    const uchar4* __restrict__ fcellP, const float4* __restrict__ fwtP,
    const short* __restrict__ Y0,
    const int* __restrict__ btstart, const int* __restrict__ bsrcP,
    const uchar4* __restrict__ bcellP, const float4* __restrict__ bwtP,
    const short* __restrict__ Y1,
    float* __restrict__ ans0, int c0, int CC, int init, int fin) {
  int lane = threadIdx.x & 63;
  int t = blockIdx.x * 4 + (threadIdx.x >> 6);
  int co = lane & 31;
  int hi = lane >> 5;
  int YW = CC * 32;
  float f = 0.f;
  int s = ftstart[t], e1 = ftstart[t + 1];
  for (int idx = s; idx < e1; idx++) {
    int src = fsrcP[idx];
    uchar4 c4 = fcellP[idx];
    float4 w4 = fwtP[idx];
    const short* yr = Y0 + (size_t)src * YW + co;
    int ca = (hi ? c4.y : c4.x) - c0;
    int cb = (hi ? c4.w : c4.z) - c0;
    float wa = hi ? w4.y : w4.x;
    float wb = hi ? w4.w : w4.z;
    if ((unsigned)ca < (unsigned)CC) f += wa * b2f(yr[ca * 32]);
    if ((unsigned)cb < (unsigned)CC) f += wb * b2f(yr[cb * 32]);
  }
  f += __shfl_xor(f, 32, 64);
  float b = 0.f;
  s = btstart[t]; e1 = btstart[t + 1];
  for (int idx = s; idx < e1; idx++) {
    int src = bsrcP[idx];
    uchar4 c4 = bcellP[idx];
    float4 w4 = bwtP[idx];
    const short* yr = Y1 + (size_t)src * YW + co;
    int ca = (hi ? c4.y : c4.x) - c0;
    int cb = (hi ? c4.w : c4.z) - c0;
    float wa = hi ? w4.y : w4.x;
    float wb = hi ? w4.w : w4.z;
    if ((unsigned)ca < (unsigned)CC) b += wa * b2f(yr[ca * 32]);
    if ((unsigned)cb < (unsigned)CC) b += wb * b2f(yr[cb * 32]);
  }
  b += __shfl_xor(b, 32, 64);
  if (!init) { f += ans0[t * 96 + 32 + co]; b += ans0[t * 96 + 64 + co]; }
  if (fin) { f = fmaxf(f, 0.f); b = fmaxf(b, 0.f); }
  if (lane < 32) {
    ans0[t * 96 + 32 + co] = f;
    ans0[t * 96 + 64 + co] = b;
    if (init) {
      float4 fv = *(const float4*)(ff + t * 4);
      float a = fv.x * fc0[co] + fv.y * fc0[32 + co] + fv.z * fc0[64 + co] +
                fv.w * fc0[96 + co];
      ans0[t * 96 + co] = fmaxf(a, 0.f);
    }
  }
}

// ---------------------------------------------------------------------------
// Phase B stages 2/3: dest = relu(conv_gather + xin@fc (+resid)).
// ---------------------------------------------------------------------------
template <int CIN, int RESID>
__global__ void __launch_bounds__(256, 4) b23(
    const float* __restrict__ xin, const float* __restrict__ fc,
    const int* __restrict__ ftstart, const int* __restrict__ esrcP,
    const uchar4* __restrict__ ecellP, const float4* __restrict__ ewtP,
    const short* __restrict__ Y, const float* __restrict__ resid,
    float* __restrict__ dest, int c0, int CC, int init, int fin) {
  int lane = threadIdx.x & 63;
  int t = blockIdx.x * 4 + (threadIdx.x >> 6);
  int YW = CC * 64;
  float acc;
  if (init) {
    acc = RESID ? resid[(size_t)t * 64 + lane] : 0.f;
    const float4* __restrict__ xr = (const float4*)(xin + (size_t)t * CIN);
#pragma unroll
    for (int q = 0; q < CIN / 4; q++) {
      float4 xv = xr[q];
      acc = fmaf(xv.x, fc[(4 * q + 0) * 64 + lane], acc);
      acc = fmaf(xv.y, fc[(4 * q + 1) * 64 + lane], acc);
      acc = fmaf(xv.z, fc[(4 * q + 2) * 64 + lane], acc);
      acc = fmaf(xv.w, fc[(4 * q + 3) * 64 + lane], acc);
    }
  } else {
    acc = dest[(size_t)t * 64 + lane];
  }
  int s = ftstart[t], e1 = ftstart[t + 1];
  for (int idx = s; idx < e1; idx++) {
    int src = esrcP[idx];
    uchar4 c4 = ecellP[idx];
    float4 w4 = ewtP[idx];
    const short* yr = Y + (size_t)src * YW + lane;
    int ca = c4.x - c0, cb = c4.y - c0, cc_ = c4.z - c0, cd = c4.w - c0;
    if ((unsigned)ca < (unsigned)CC) acc += w4.x * b2f(yr[ca * 64]);
    if ((unsigned)cb < (unsigned)CC) acc += w4.y * b2f(yr[cb * 64]);
    if ((unsigned)cc_ < (unsigned)CC) acc += w4.z * b2f(yr[cc_ * 64]);
    if ((unsigned)cd < (unsigned)CC) acc += w4.w * b2f(yr[cd * 64]);
  }
  dest[(size_t)t * 64 + lane] = fin ? fmaxf(acc, 0.f) : acc;
}

// ---------------------------------------------------------------------------
// Phase B stage 4: out[t] = gather(Y4) + ans2@fc3. lane = flat instance slot.
// ---------------------------------------------------------------------------
__global__ void __launch_bounds__(256, 4) b4_stage4(
    const float* __restrict__ ans2, const float* __restrict__ fc3,
    const int* __restrict__ ftstart, const int* __restrict__ esrcP,
    const unsigned char* __restrict__ ecellFlat, const float* __restrict__ ewtFlat,
    const float* __restrict__ Y4, float* __restrict__ partial,
    float* __restrict__ outp, int c0, int CC, int init, int fin) {
  int lane = threadIdx.x & 63;
  int t = blockIdx.x * 4 + (threadIdx.x >> 6);
  int s4 = ftstart[t] * 4, e4 = ftstart[t + 1] * 4;
  float m0 = 0.f, m1 = 0.f;
  for (int q = s4 + lane; q < e4; q += 64) {
    int src = esrcP[q >> 2];
    int cell = (int)ecellFlat[q] - c0;
    float w = ewtFlat[q];
    if ((unsigned)cell < (unsigned)CC) {
      float2 mm = *(const float2*)(Y4 + (size_t)src * (CC * 2) + cell * 2);
      m0 += w * mm.x;
      m1 += w * mm.y;
    }
  }
  if (init) {
    float a = ans2[(size_t)t * 64 + lane];
    m0 += a * fc3[lane * 2 + 0];
    m1 += a * fc3[lane * 2 + 1];
  }
#pragma unroll
  for (int off = 32; off > 0; off >>= 1) {
    m0 += __shfl_xor(m0, off, 64);
    m1 += __shfl_xor(m1, off, 64);
  }
  if (lane == 0) {
    if (!init) { m0 += partial[t * 2]; m1 += partial[t * 2 + 1]; }
    if (fin) { outp[t * 2] = m0; outp[t * 2 + 1] = m1; }
    else { partial[t * 2] = m0; partial[t * 2 + 1] = m1; }
  }
}

// ---------------------------------------------------------------------------
extern "C" void kernel_launch(void* const* d_in, const int* in_sizes, int n_in,
                              void* d_out, int out_size, void* d_ws, size_t ws_size,
                              hipStream_t stream) {
  const float* fp  = (const float*)d_in[0];
  const float* bp  = (const float*)d_in[1];
  const float* ff  = (const float*)d_in[2];
  const float* bfe = (const float*)d_in[3];
  const float* sup = (const float*)d_in[4];
  const int* fi  = (const int*)d_in[5];
  const int* fj  = (const int*)d_in[6];
  const int* bfi = (const int*)d_in[7];
  const int* bb  = (const int*)d_in[8];
  const float* W0 = (const float*)d_in[9];
  const float* W1 = (const float*)d_in[10];
  const float* W2 = (const float*)d_in[11];
  const float* W3 = (const float*)d_in[12];
  const float* W4 = (const float*)d_in[13];
  const float* fc0 = (const float*)d_in[14];
  const float* fc1 = (const float*)d_in[15];
  const float* fc2 = (const float*)d_in[16];
  const float* fc3 = (const float*)d_in[17];
  float* out = (float*)d_out;

  char* w = (char*)d_ws;
  size_t off = 0;
  auto alloc = [&](size_t bytes) {
    char* p = w + off;
    off += (bytes + 255) & ~size_t(255);
    return p;
  };
  float* ans0   = (float*)alloc((size_t)NF * 96 * 4);
  float* ans1   = (float*)alloc((size_t)NF * 64 * 4);
  float* ans2   = (float*)alloc((size_t)NF * 64 * 4);
  float* outpre = (float*)alloc((size_t)NF * 2 * 4);
  uchar4* fcells = (uchar4*)alloc((size_t)EF * 4);
  float4* fwts   = (float4*)alloc((size_t)EF * 16);
  uchar4* bcells = (uchar4*)alloc((size_t)EB * 4);
  float4* bwts   = (float4*)alloc((size_t)EB * 16);
  int* fthist  = (int*)alloc((size_t)NF * 4);
  int* ftstart = (int*)alloc((size_t)(NF + 1) * 4);
  int* ftcur   = (int*)alloc((size_t)NF * 4);
  int* ftedges = (int*)alloc((size_t)EF * 4);
  int* bthist  = (int*)alloc((size_t)NF * 4);
  int* btstart = (int*)alloc((size_t)(NF + 1) * 4);
  int* btcur   = (int*)alloc((size_t)NF * 4);
  int* btedges = (int*)alloc((size_t)EB * 4);
  int* fsrcP    = (int*)alloc((size_t)EF * 4);
  uchar4* fcellP = (uchar4*)alloc((size_t)EF * 4);
  float4* fwtP   = (float4*)alloc((size_t)EF * 16);
  int* bsrcP    = (int*)alloc((size_t)EB * 4);
  uchar4* bcellP = (uchar4*)alloc((size_t)EB * 4);
  float4* bwtP   = (float4*)alloc((size_t)EB * 16);
  short* Xh = (short*)alloc((size_t)NF * 96 * 2);
  short* BT = (short*)alloc((size_t)4096 * 96 * 2);
  // Y region: rest of workspace, chunked over cells.
  char* Yreg = w + off;
  size_t avail = (ws_size > off) ? (ws_size - off) : 0;
  size_t percell = (size_t)NF * 64 * 2;  // 2.1 MB per cell (largest user: bf16 Y)
  int CC = 64;
  while (CC > 2 && (size_t)CC * percell > avail) CC >>= 1;
  int S = 64 / CC;
  short* Y  = (short*)Yreg;                              // [NF][CC*64] bf16
  short* Y0 = (short*)Yreg;                              // [NF][CC*32] bf16
  short* Y1 = Y0 + (size_t)NF * CC * 32;                 // [NB][CC*32] bf16
  float* Y4 = (float*)Yreg;                              // [NF][CC*2] fp32

  hipMemsetAsync(fthist, 0, (size_t)NF * 4, stream);
  hipMemsetAsync(bthist, 0, (size_t)NF * 4, stream);

  // Basis + target-CSR + payload (graph prep, reused by all stages)
  basis_kernel<<<FBLK, 256, 0, stream>>>(fp, fp, fi, fj, sup, -1.f, fcells, fwts);
  basis_kernel<<<BBLK, 256, 0, stream>>>(fp, bp, bfi, bb, sup, 1.f, bcells, bwts);
  tgt_hist<<<FBLK, 256, 0, stream>>>(fi, EF, fthist);
  tgt_hist<<<BBLK, 256, 0, stream>>>(bfi, EB, bthist);
  csr_scan<<<1, 1024, 0, stream>>>(fthist, ftstart, ftcur);
  csr_scan<<<1, 1024, 0, stream>>>(bthist, btstart, btcur);
  tgt_scatter<<<FBLK, 256, 0, stream>>>(fi, EF, ftcur, ftedges);
  tgt_scatter<<<BBLK, 256, 0, stream>>>(bfi, EB, btcur, btedges);
  build_payload<<<FBLK, 256, 0, stream>>>(ftedges, fj, fcells, fwts, EF, fsrcP, fcellP, fwtP);
  build_payload<<<BBLK, 256, 0, stream>>>(btedges, bb, bcells, bwts, EB, bsrcP, bcellP, bwtP);

  // Stage 1: dense per-(node,cell) conv (K=4) + gather-assemble ans0
  for (int c = 0; c < S; c++) {
    int c0 = c * CC;
    conv_k4_c32<<<dim3(NF * 32 / 256, CC), 256, 0, stream>>>(ff, W0, Y0, c0, CC);
    conv_k4_c32<<<dim3(NB * 32 / 256, CC), 256, 0, stream>>>(bfe, W1, Y1, c0, CC);
    b1_stage1<<<NF / 4, 256, 0, stream>>>(ff, fc0, ftstart, fsrcP, fcellP, fwtP, Y0,
                                          btstart, bsrcP, bcellP, bwtP, Y1, ans0,
                                          c0, CC, c == 0, c == S - 1);
  }
  // Stage 2: Y = bf16(ans0) @ bf16(W2cat) via MFMA; ans1 = relu(gather + ans0@fc1)
  cvt_f2b<<<(NF * 96 + 255) / 256, 256, 0, stream>>>(ans0, Xh, NF * 96);
  buildBT<<<(4096 * 96 + 255) / 256, 256, 0, stream>>>(W2, BT, 96);
  for (int c = 0; c < S; c++) {
    int c0 = c * CC;
    gemm_bf16<96><<<dim3(NF / 128, CC * 64 / 128), 256, 0, stream>>>(
        Xh, BT + (size_t)c0 * 64 * 96, Y, CC * 64);
    b23<96, 0><<<NF / 4, 256, 0, stream>>>(ans0, fc1, ftstart, fsrcP, fcellP, fwtP,
                                           Y, nullptr, ans1, c0, CC, c == 0, c == S - 1);
  }
  // Stage 3: ans2 = relu(gather + ans1@fc2 + ans1)
  cvt_f2b<<<(NF * 64 + 255) / 256, 256, 0, stream>>>(ans1, Xh, NF * 64);
  buildBT<<<(4096 * 64 + 255) / 256, 256, 0, stream>>>(W3, BT, 64);
  for (int c = 0; c < S; c++) {
    int c0 = c * CC;
    gemm_bf16<64><<<dim3(NF / 128, CC * 64 / 128), 256, 0, stream>>>(
        Xh, BT + (size_t)c0 * 64 * 64, Y, CC * 64);
    b23<64, 1><<<NF / 4, 256, 0, stream>>>(ans1, fc2, ftstart, fsrcP, fcellP, fwtP,
                                           Y, ans1, ans2, c0, CC, c == 0, c == S - 1);
  }
  // Stage 4: dense conv (K=64, cout=2/cell, fp32) + gather + ans2@fc3
  for (int c = 0; c < S; c++) {
    int c0 = c * CC;
    conv_k64_c2<<<dim3(NF * 2 / 256, CC), 256, 0, stream>>>(ans2, W4, Y4, c0, CC);
    b4_stage4<<<NF / 4, 256, 0, stream>>>(ans2, fc3, ftstart, fsrcP,
                                          (const unsigned char*)fcellP, (const float*)fwtP,
                                          Y4, outpre, out, c0, CC, c == 0, c == S - 1);
  }
}

// Round 6
// 513.777 us; speedup vs baseline: 6.1254x; 1.2812x over previous
//
#include <hip/hip_runtime.h>

#define NF 16384
#define NB 4096
#define EF 262144
#define EB 65536
#define FBLK 1024   // EF/256
#define BBLK 256    // EB/256

typedef __attribute__((ext_vector_type(8))) short bf16x8;
typedef __attribute__((ext_vector_type(4))) float f32x4;

__device__ __forceinline__ short f2b(float f) {
  unsigned u = __float_as_uint(f);
  u += 0x7fff + ((u >> 16) & 1);   // RNE
  return (short)(u >> 16);
}
__device__ __forceinline__ float b2f_lo(unsigned u) {
  return __uint_as_float(u << 16);
}
__device__ __forceinline__ float b2f_hi(unsigned u) {
  return __uint_as_float(u & 0xffff0000u);
}

// ---------------------------------------------------------------------------
// Per-edge tent-basis cells + bilinear weights.
// ---------------------------------------------------------------------------
__global__ void __launch_bounds__(256) basis_kernel(
    const float* __restrict__ posT, const float* __restrict__ posS,
    const int* __restrict__ tgt, const int* __restrict__ src,
    const float* __restrict__ supportp, float sign,
    unsigned char* __restrict__ cells, float4* __restrict__ wts) {
  int e = blockIdx.x * 256 + threadIdx.x;
  float inv_sup = 1.0f / supportp[0];
  int ti = tgt[e], si = src[e];
  const float2* pT2 = (const float2*)posT;
  const float2* pS2 = (const float2*)posS;
  float2 pt = pT2[ti];
  float2 ps = pS2[si];
  // d = sign*(src-tgt)/support; sign=-1 fluid, +1 boundary. (-1)*(+0) = -0
  // preserves reference signed zeros for self-edges (atan2(-0,-0) = -pi).
  float dx = sign * ((ps.x - pt.x) * inv_sup);
  float dy = sign * ((ps.y - pt.y) * inv_sup);
  dx = fminf(fmaxf(dx, -1.f), 1.f);
  dy = fminf(fmaxf(dy, -1.f), 1.f);
  float r = sqrtf(dx * dx + dy * dy + 1e-12f);
  float theta;
  if (dx == 0.0f && dy == 0.0f) {
    float mag = __builtin_signbitf(dx) ? 3.14159265358979323846f : 0.0f;
    theta = __builtin_signbitf(dy) ? -mag : mag;
  } else {
    theta = atan2f(dy, dx);
  }
  float u = 2.f * r - 1.f;
  float v = theta * (1.f / 3.14159265358979323846f);
  float tu = (u + 1.f) * 3.5f;
  float tv = (v + 1.f) * 3.5f;
  int iu = min(max((int)floorf(tu), 0), 6);
  int iv = min(max((int)floorf(tv), 0), 6);
  float wu0 = fmaxf(0.f, 1.f - fabsf(tu - (float)iu));
  float wu1 = fmaxf(0.f, 1.f - fabsf(tu - (float)(iu + 1)));
  float wv0 = fmaxf(0.f, 1.f - fabsf(tv - (float)iv));
  float wv1 = fmaxf(0.f, 1.f - fabsf(tv - (float)(iv + 1)));
  cells[e] = (unsigned char)(iu * 8 + iv);
  wts[e] = make_float4(wu0 * wv0, wu0 * wv1, wu1 * wv0, wu1 * wv1);
}

// ---------------------------------------------------------------------------
// Target CSR build.
// ---------------------------------------------------------------------------
__global__ void __launch_bounds__(256) tgt_hist(const int* __restrict__ tgt, int n,
                                                int* __restrict__ hist) {
  int e = blockIdx.x * 256 + threadIdx.x;
  if (e < n) atomicAdd(hist + tgt[e], 1);
}

__global__ void __launch_bounds__(1024) csr_scan(const int* __restrict__ hist,
                                                 int* __restrict__ start,
                                                 int* __restrict__ cursor) {
  __shared__ int wtot[16];
  int t = threadIdx.x;
  int lane = t & 63, wv = t >> 6;
  int base = t * 16;
  int vals[16];
  int s = 0;
#pragma unroll
  for (int k = 0; k < 16; k++) { vals[k] = hist[base + k]; s += vals[k]; }
  int ss = s;
  for (int off = 1; off < 64; off <<= 1) {
    int o = __shfl_up(ss, off, 64);
    if (lane >= off) ss += o;
  }
  if (lane == 63) wtot[wv] = ss;
  __syncthreads();
  if (t < 16) {
    int v = wtot[t];
    int vv = v;
    for (int off = 1; off < 16; off <<= 1) {
      int o = __shfl_up(vv, off, 64);
      if (t >= off) vv += o;
    }
    wtot[t] = vv - v;
  }
  __syncthreads();
  int run = ss - s + wtot[wv];
#pragma unroll
  for (int k = 0; k < 16; k++) { start[base + k] = run; cursor[base + k] = run; run += vals[k]; }
  if (t == 1023) start[16384] = run;
}

__global__ void __launch_bounds__(256) tgt_scatter(const int* __restrict__ tgt, int n,
                                                   int* __restrict__ cursor,
                                                   int* __restrict__ edges) {
  int e = blockIdx.x * 256 + threadIdx.x;
  if (e < n) { int p = atomicAdd(cursor + tgt[e], 1); edges[p] = e; }
}

// Packed per-CSR-slot payload: (src | c00<<14) + float4 weights.
__global__ void __launch_bounds__(256) build_payload(
    const int* __restrict__ edges, const int* __restrict__ srcarr,
    const unsigned char* __restrict__ cells, const float4* __restrict__ wts, int n,
    unsigned* __restrict__ epk, float4* __restrict__ ewt) {
  int idx = blockIdx.x * 256 + threadIdx.x;
  if (idx < n) {
    int e = edges[idx];
    epk[idx] = (unsigned)srcarr[e] | ((unsigned)cells[e] << 14);
    ewt[idx] = wts[e];
  }
}

// ---------------------------------------------------------------------------
// fp32 -> bf16 ; B^T weight build.
// ---------------------------------------------------------------------------
__global__ void __launch_bounds__(256) cvt_f2b(const float* __restrict__ x,
                                               short* __restrict__ y, int n) {
  int i = blockIdx.x * 256 + threadIdx.x;
  if (i < n) y[i] = f2b(x[i]);
}

__global__ void __launch_bounds__(256) buildBT(const float* __restrict__ W,
                                               short* __restrict__ BT, int K) {
  int tid = blockIdx.x * 256 + threadIdx.x;
  if (tid >= 4096 * K) return;
  int k = tid % K, n = tid / K;
  BT[tid] = f2b(W[((size_t)(n >> 6) * K + k) * 64 + (n & 63)]);
}

// ---------------------------------------------------------------------------
// Dense MFMA GEMM (unchanged; verified m89/m91 layout).
// ---------------------------------------------------------------------------
template <int K>
__global__ void __launch_bounds__(256, 2) gemm_bf16(
    const short* __restrict__ A, const short* __restrict__ BT,
    short* __restrict__ C, int N) {
  int lane = threadIdx.x & 63;
  int w = threadIdx.x >> 6;
  int m0 = blockIdx.x * 128 + (w & 1) * 64;
  int n0 = blockIdx.y * 128 + (w >> 1) * 64;
  int fr = lane & 15;
  int kg = lane >> 4;
  f32x4 acc[4][4] = {};
#pragma unroll
  for (int kc = 0; kc < K; kc += 32) {
    bf16x8 a[4], b[4];
#pragma unroll
    for (int i = 0; i < 4; i++) {
      a[i] = *(const bf16x8*)(A + (size_t)(m0 + i * 16 + fr) * K + kc + kg * 8);
      b[i] = *(const bf16x8*)(BT + (size_t)(n0 + i * 16 + fr) * K + kc + kg * 8);
    }
#pragma unroll
    for (int i = 0; i < 4; i++)
#pragma unroll
      for (int j = 0; j < 4; j++)
        acc[i][j] = __builtin_amdgcn_mfma_f32_16x16x32_bf16(a[i], b[j], acc[i][j], 0, 0, 0);
  }
#pragma unroll
  for (int i = 0; i < 4; i++) {
    int row = m0 + i * 16 + (lane >> 4) * 4;
#pragma unroll
    for (int j = 0; j < 4; j++) {
      int col = n0 + j * 16 + (lane & 15);
#pragma unroll
      for (int r = 0; r < 4; r++)
        C[(size_t)(row + r) * N + col] = f2b(acc[i][j][r]);
    }
  }
}

// ---------------------------------------------------------------------------
// Stage-1 dense conv (K=4, 32 couts/cell).
// ---------------------------------------------------------------------------
__global__ void __launch_bounds__(256) conv_k4_c32(
    const float* __restrict__ x, const float* __restrict__ W /*[64][4][32]*/,
    short* __restrict__ Y, int c0, int CC) {
  int t = threadIdx.x;
  int co = t & 31;
  int n = (blockIdx.x * 256 + t) >> 5;
  int cellL = blockIdx.y;
  const float* Wc = W + (c0 + cellL) * 128 + co;
  float4 xv = *(const float4*)(x + (size_t)n * 4);
  float a = xv.x * Wc[0] + xv.y * Wc[32] + xv.z * Wc[64] + xv.w * Wc[96];
  Y[(size_t)n * (CC * 32) + cellL * 32 + co] = f2b(a);
}

// ---------------------------------------------------------------------------
// Stage-4 dense conv (K=64, 2 couts/cell, fp32).
// ---------------------------------------------------------------------------
__global__ void __launch_bounds__(256) conv_k64_c2(
    const float* __restrict__ x, const float* __restrict__ W4 /*[64][64][2]*/,
    float* __restrict__ Y4, int c0, int CC) {
  int t = threadIdx.x;
  int q = t & 1;
  int n = (blockIdx.x * 256 + t) >> 1;
  int cellL = blockIdx.y;
  const float* wr = W4 + (size_t)(c0 + cellL) * 128 + q;
  const float4* xr = (const float4*)(x + (size_t)n * 64);
  float a = 0.f;
#pragma unroll
  for (int k = 0; k < 16; k++) {
    float4 xv = xr[k];
    a += xv.x * wr[(4 * k) * 2] + xv.y * wr[(4 * k + 1) * 2] +
         xv.z * wr[(4 * k + 2) * 2] + xv.w * wr[(4 * k + 3) * 2];
  }
  Y4[(size_t)n * (CC * 2) + cellL * 2 + q] = a;
}

// ---------------------------------------------------------------------------
// Phase B stage 1. Pair-width gather: quarter q of the wave covers cell
// c00+{0,1,8,9}[q]; lane loads ushort2 (co pair 2*(lane&15)). Partial sums
// combined AFTER the edge loops with shfl_xor(16)+shfl_xor(32).
// Writers: lanes 0..15 fluid cols 32..63; 16..31 bdy cols 64..95;
// 32..47 lin cols 0..31 (init only).
// ---------------------------------------------------------------------------
__global__ void __launch_bounds__(256, 4) b1_stage1(
    const float* __restrict__ ff, const float* __restrict__ fc0,
    const int* __restrict__ ftstart, const unsigned* __restrict__ fpk,
    const float4* __restrict__ fwt, const short* __restrict__ Y0,
    const int* __restrict__ btstart, const unsigned* __restrict__ bpk,
    const float4* __restrict__ bwt, const short* __restrict__ Y1,
    float* __restrict__ ans0, int c0, int CC, int init, int fin) {
  int lane = threadIdx.x & 63;
  int t = blockIdx.x * 4 + (threadIdx.x >> 6);
  int q = lane >> 4;
  int p = lane & 15;              // co pair index
  int cofs = (q & 1) + (q >> 1) * 8;
  int YW = CC * 32;
  float2 fa = make_float2(0.f, 0.f);
  int s = ftstart[t], e1 = ftstart[t + 1];
  for (int idx = s; idx < e1; idx++) {
    unsigned pk = fpk[idx];
    float4 w4 = fwt[idx];
    int src = pk & 16383;
    int cell = (int)(pk >> 14) + cofs - c0;
    float wq = (q == 0) ? w4.x : (q == 1) ? w4.y : (q == 2) ? w4.z : w4.w;
    if ((unsigned)cell < (unsigned)CC) {
      unsigned raw = *(const unsigned*)(Y0 + (size_t)src * YW + cell * 32 + 2 * p);
      fa.x = fmaf(wq, b2f_lo(raw), fa.x);
      fa.y = fmaf(wq, b2f_hi(raw), fa.y);
    }
  }
  float2 ba = make_float2(0.f, 0.f);
  s = btstart[t]; e1 = btstart[t + 1];
  for (int idx = s; idx < e1; idx++) {
    unsigned pk = bpk[idx];
    float4 w4 = bwt[idx];
    int src = pk & 16383;
    int cell = (int)(pk >> 14) + cofs - c0;
    float wq = (q == 0) ? w4.x : (q == 1) ? w4.y : (q == 2) ? w4.z : w4.w;
    if ((unsigned)cell < (unsigned)CC) {
      unsigned raw = *(const unsigned*)(Y1 + (size_t)src * YW + cell * 32 + 2 * p);
      ba.x = fmaf(wq, b2f_lo(raw), ba.x);
      ba.y = fmaf(wq, b2f_hi(raw), ba.y);
    }
  }
  // cross-quarter combine
  fa.x += __shfl_xor(fa.x, 16, 64); fa.y += __shfl_xor(fa.y, 16, 64);
  fa.x += __shfl_xor(fa.x, 32, 64); fa.y += __shfl_xor(fa.y, 32, 64);
  ba.x += __shfl_xor(ba.x, 16, 64); ba.y += __shfl_xor(ba.y, 16, 64);
  ba.x += __shfl_xor(ba.x, 32, 64); ba.y += __shfl_xor(ba.y, 32, 64);
  if (lane < 16) {
    float2* dst = (float2*)(ans0 + (size_t)t * 96 + 32 + 2 * p);
    if (!init) { float2 d = *dst; fa.x += d.x; fa.y += d.y; }
    if (fin) { fa.x = fmaxf(fa.x, 0.f); fa.y = fmaxf(fa.y, 0.f); }
    *dst = fa;
  } else if (lane < 32) {
    float2* dst = (float2*)(ans0 + (size_t)t * 96 + 64 + 2 * p);
    if (!init) { float2 d = *dst; ba.x += d.x; ba.y += d.y; }
    if (fin) { ba.x = fmaxf(ba.x, 0.f); ba.y = fmaxf(ba.y, 0.f); }
    *dst = ba;
  } else if (lane < 48 && init) {
    float4 fv = *(const float4*)(ff + (size_t)t * 4);
    float l0 = fv.x * fc0[2 * p] + fv.y * fc0[32 + 2 * p] +
               fv.z * fc0[64 + 2 * p] + fv.w * fc0[96 + 2 * p];
    float l1 = fv.x * fc0[2 * p + 1] + fv.y * fc0[32 + 2 * p + 1] +
               fv.z * fc0[64 + 2 * p + 1] + fv.w * fc0[96 + 2 * p + 1];
    *(float2*)(ans0 + (size_t)t * 96 + 2 * p) = make_float2(fmaxf(l0, 0.f), fmaxf(l1, 0.f));
  }
}

// ---------------------------------------------------------------------------
// Phase B stages 2/3. Quad-width gather: one ushort4 load per edge per lane
// (512B per wave per edge); fc-GEMM folded into the same quarter-split
// reduction (quarter q handles k in [q*CIN/4,(q+1)*CIN/4)).
// ---------------------------------------------------------------------------
template <int CIN, int RESID>
__global__ void __launch_bounds__(256, 4) b23(
    const float* __restrict__ xin, const float* __restrict__ fc,
    const int* __restrict__ ftstart, const unsigned* __restrict__ epk,
    const float4* __restrict__ ewt, const short* __restrict__ Y,
    const float* __restrict__ resid, float* __restrict__ dest,
    int c0, int CC, int init, int fin) {
  int lane = threadIdx.x & 63;
  int t = blockIdx.x * 4 + (threadIdx.x >> 6);
  int q = lane >> 4;
  int sub = lane & 15;            // co quad index (cos 4*sub..4*sub+3)
  int cofs = (q & 1) + (q >> 1) * 8;
  int YW = CC * 64;
  float a0 = 0.f, a1 = 0.f, a2 = 0.f, a3 = 0.f;
  if (init) {
    // fc partial over this quarter's k-range
    const float* xr = xin + (size_t)t * CIN;
#pragma unroll
    for (int kk = 0; kk < CIN / 4; kk++) {
      int k = q * (CIN / 4) + kk;
      float xv = xr[k];
      float4 fv = *(const float4*)(fc + (size_t)k * 64 + 4 * sub);
      a0 = fmaf(xv, fv.x, a0);
      a1 = fmaf(xv, fv.y, a1);
      a2 = fmaf(xv, fv.z, a2);
      a3 = fmaf(xv, fv.w, a3);
    }
  }
  int s = ftstart[t], e1 = ftstart[t + 1];
  int idx = s;
  for (; idx + 1 < e1; idx += 2) {
    unsigned pkA = epk[idx], pkB = epk[idx + 1];
    float4 wA = ewt[idx], wB = ewt[idx + 1];
    int srcA = pkA & 16383, srcB = pkB & 16383;
    int cellA = (int)(pkA >> 14) + cofs - c0;
    int cellB = (int)(pkB >> 14) + cofs - c0;
    float wqA = (q == 0) ? wA.x : (q == 1) ? wA.y : (q == 2) ? wA.z : wA.w;
    float wqB = (q == 0) ? wB.x : (q == 1) ? wB.y : (q == 2) ? wB.z : wB.w;
    bool vA = (unsigned)cellA < (unsigned)CC;
    bool vB = (unsigned)cellB < (unsigned)CC;
    uint2 rA = make_uint2(0, 0), rB = make_uint2(0, 0);
    if (vA) rA = *(const uint2*)(Y + (size_t)srcA * YW + cellA * 64 + 4 * sub);
    if (vB) rB = *(const uint2*)(Y + (size_t)srcB * YW + cellB * 64 + 4 * sub);
    a0 = fmaf(wqA, b2f_lo(rA.x), a0); a1 = fmaf(wqA, b2f_hi(rA.x), a1);
    a2 = fmaf(wqA, b2f_lo(rA.y), a2); a3 = fmaf(wqA, b2f_hi(rA.y), a3);
    a0 = fmaf(wqB, b2f_lo(rB.x), a0); a1 = fmaf(wqB, b2f_hi(rB.x), a1);
    a2 = fmaf(wqB, b2f_lo(rB.y), a2); a3 = fmaf(wqB, b2f_hi(rB.y), a3);
  }
  if (idx < e1) {
    unsigned pk = epk[idx];
    float4 w4 = ewt[idx];
    int src = pk & 16383;
    int cell = (int)(pk >> 14) + cofs - c0;
    float wq = (q == 0) ? w4.x : (q == 1) ? w4.y : (q == 2) ? w4.z : w4.w;
    if ((unsigned)cell < (unsigned)CC) {
      uint2 r = *(const uint2*)(Y + (size_t)src * YW + cell * 64 + 4 * sub);
      a0 = fmaf(wq, b2f_lo(r.x), a0); a1 = fmaf(wq, b2f_hi(r.x), a1);
      a2 = fmaf(wq, b2f_lo(r.y), a2); a3 = fmaf(wq, b2f_hi(r.y), a3);
    }
  }
  // cross-quarter combine (also sums the fc k-range partials)
  a0 += __shfl_xor(a0, 16, 64); a1 += __shfl_xor(a1, 16, 64);
  a2 += __shfl_xor(a2, 16, 64); a3 += __shfl_xor(a3, 16, 64);
  a0 += __shfl_xor(a0, 32, 64); a1 += __shfl_xor(a1, 32, 64);
  a2 += __shfl_xor(a2, 32, 64); a3 += __shfl_xor(a3, 32, 64);
  if (lane < 16) {
    float4* dst = (float4*)(dest + (size_t)t * 64 + 4 * sub);
    if (!init) {
      float4 d = *dst;
      a0 += d.x; a1 += d.y; a2 += d.z; a3 += d.w;
    }
    if (RESID && init) {
      float4 rd = *(const float4*)(resid + (size_t)t * 64 + 4 * sub);
      a0 += rd.x; a1 += rd.y; a2 += rd.z; a3 += rd.w;
    }
    if (fin) {
      a0 = fmaxf(a0, 0.f); a1 = fmaxf(a1, 0.f);
      a2 = fmaxf(a2, 0.f); a3 = fmaxf(a3, 0.f);
    }
    *dst = make_float4(a0, a1, a2, a3);
  }
}

// ---------------------------------------------------------------------------
// Phase B stage 4: out[t] = gather(Y4) + ans2@fc3. lane = flat instance slot.
// ---------------------------------------------------------------------------
__global__ void __launch_bounds__(256, 4) b4_stage4(
    const float* __restrict__ ans2, const float* __restrict__ fc3,
    const int* __restrict__ ftstart, const unsigned* __restrict__ epk,
    const float4* __restrict__ ewt, const float* __restrict__ Y4,
    float* __restrict__ partial, float* __restrict__ outp,
    int c0, int CC, int init, int fin) {
  int lane = threadIdx.x & 63;
  int t = blockIdx.x * 4 + (threadIdx.x >> 6);
  int s4 = ftstart[t] * 4, e4 = ftstart[t + 1] * 4;
  float m0 = 0.f, m1 = 0.f;
  for (int fq = s4 + lane; fq < e4; fq += 64) {
    int idx = fq >> 2, j = fq & 3;
    unsigned pk = epk[idx];
    float4 w4 = ewt[idx];
    int src = pk & 16383;
    int cell = (int)(pk >> 14) + (j & 1) + (j >> 1) * 8 - c0;
    float w = (j == 0) ? w4.x : (j == 1) ? w4.y : (j == 2) ? w4.z : w4.w;
    if ((unsigned)cell < (unsigned)CC) {
      float2 mm = *(const float2*)(Y4 + (size_t)src * (CC * 2) + cell * 2);
      m0 += w * mm.x;
      m1 += w * mm.y;
    }
  }
  if (init) {
    float a = ans2[(size_t)t * 64 + lane];
    m0 += a * fc3[lane * 2 + 0];
    m1 += a * fc3[lane * 2 + 1];
  }
#pragma unroll
  for (int off = 32; off > 0; off >>= 1) {
    m0 += __shfl_xor(m0, off, 64);
    m1 += __shfl_xor(m1, off, 64);
  }
  if (lane == 0) {
    if (!init) { m0 += partial[t * 2]; m1 += partial[t * 2 + 1]; }
    if (fin) { outp[t * 2] = m0; outp[t * 2 + 1] = m1; }
    else { partial[t * 2] = m0; partial[t * 2 + 1] = m1; }
  }
}

// ---------------------------------------------------------------------------
extern "C" void kernel_launch(void* const* d_in, const int* in_sizes, int n_in,
                              void* d_out, int out_size, void* d_ws, size_t ws_size,
                              hipStream_t stream) {
  const float* fp  = (const float*)d_in[0];
  const float* bp  = (const float*)d_in[1];
  const float* ff  = (const float*)d_in[2];
  const float* bfe = (const float*)d_in[3];
  const float* sup = (const float*)d_in[4];
  const int* fi  = (const int*)d_in[5];
  const int* fj  = (const int*)d_in[6];
  const int* bfi = (const int*)d_in[7];
  const int* bb  = (const int*)d_in[8];
  const float* W0 = (const float*)d_in[9];
  const float* W1 = (const float*)d_in[10];
  const float* W2 = (const float*)d_in[11];
  const float* W3 = (const float*)d_in[12];
  const float* W4 = (const float*)d_in[13];
  const float* fc0 = (const float*)d_in[14];
  const float* fc1 = (const float*)d_in[15];
  const float* fc2 = (const float*)d_in[16];
  const float* fc3 = (const float*)d_in[17];
  float* out = (float*)d_out;

  char* w = (char*)d_ws;
  size_t off = 0;
  auto alloc = [&](size_t bytes) {
    char* p = w + off;
    off += (bytes + 255) & ~size_t(255);
    return p;
  };
  float* ans0   = (float*)alloc((size_t)NF * 96 * 4);
  float* ans1   = (float*)alloc((size_t)NF * 64 * 4);
  float* ans2   = (float*)alloc((size_t)NF * 64 * 4);
  float* outpre = (float*)alloc((size_t)NF * 2 * 4);
  unsigned char* fcells = (unsigned char*)alloc((size_t)EF);
  float4* fwts   = (float4*)alloc((size_t)EF * 16);
  unsigned char* bcells = (unsigned char*)alloc((size_t)EB);
  float4* bwts   = (float4*)alloc((size_t)EB * 16);
  int* fthist  = (int*)alloc((size_t)NF * 4);
  int* ftstart = (int*)alloc((size_t)(NF + 1) * 4);
  int* ftcur   = (int*)alloc((size_t)NF * 4);
  int* ftedges = (int*)alloc((size_t)EF * 4);
  int* bthist  = (int*)alloc((size_t)NF * 4);
  int* btstart = (int*)alloc((size_t)(NF + 1) * 4);
  int* btcur   = (int*)alloc((size_t)NF * 4);
  int* btedges = (int*)alloc((size_t)EB * 4);
  unsigned* fpk  = (unsigned*)alloc((size_t)EF * 4);
  float4* fwtP   = (float4*)alloc((size_t)EF * 16);
  unsigned* bpk  = (unsigned*)alloc((size_t)EB * 4);
  float4* bwtP   = (float4*)alloc((size_t)EB * 16);
  short* Xh = (short*)alloc((size_t)NF * 96 * 2);
  short* BT = (short*)alloc((size_t)4096 * 96 * 2);
  char* Yreg = w + off;
  size_t avail = (ws_size > off) ? (ws_size - off) : 0;
  size_t percell = (size_t)NF * 64 * 2;
  int CC = 64;
  while (CC > 8 && (size_t)CC * percell > avail) CC >>= 1;  // CC multiple of 8
  int S = 64 / CC;
  short* Y  = (short*)Yreg;
  short* Y0 = (short*)Yreg;
  short* Y1 = Y0 + (size_t)NF * CC * 32;
  float* Y4 = (float*)Yreg;

  hipMemsetAsync(fthist, 0, (size_t)NF * 4, stream);
  hipMemsetAsync(bthist, 0, (size_t)NF * 4, stream);

  basis_kernel<<<FBLK, 256, 0, stream>>>(fp, fp, fi, fj, sup, -1.f, fcells, fwts);
  basis_kernel<<<BBLK, 256, 0, stream>>>(fp, bp, bfi, bb, sup, 1.f, bcells, bwts);
  tgt_hist<<<FBLK, 256, 0, stream>>>(fi, EF, fthist);
  tgt_hist<<<BBLK, 256, 0, stream>>>(bfi, EB, bthist);
  csr_scan<<<1, 1024, 0, stream>>>(fthist, ftstart, ftcur);
  csr_scan<<<1, 1024, 0, stream>>>(bthist, btstart, btcur);
  tgt_scatter<<<FBLK, 256, 0, stream>>>(fi, EF, ftcur, ftedges);
  tgt_scatter<<<BBLK, 256, 0, stream>>>(bfi, EB, btcur, btedges);
  build_payload<<<FBLK, 256, 0, stream>>>(ftedges, fj, fcells, fwts, EF, fpk, fwtP);
  build_payload<<<BBLK, 256, 0, stream>>>(btedges, bb, bcells, bwts, EB, bpk, bwtP);

  // Stage 1
  for (int c = 0; c < S; c++) {
    int c0 = c * CC;
    conv_k4_c32<<<dim3(NF * 32 / 256, CC), 256, 0, stream>>>(ff, W0, Y0, c0, CC);
    conv_k4_c32<<<dim3(NB * 32 / 256, CC), 256, 0, stream>>>(bfe, W1, Y1, c0, CC);
    b1_stage1<<<NF / 4, 256, 0, stream>>>(ff, fc0, ftstart, fpk, fwtP, Y0,
                                          btstart, bpk, bwtP, Y1, ans0,
                                          c0, CC, c == 0, c == S - 1);
  }
  // Stage 2
  cvt_f2b<<<(NF * 96 + 255) / 256, 256, 0, stream>>>(ans0, Xh, NF * 96);
  buildBT<<<(4096 * 96 + 255) / 256, 256, 0, stream>>>(W2, BT, 96);
  for (int c = 0; c < S; c++) {
    int c0 = c * CC;
    gemm_bf16<96><<<dim3(NF / 128, CC * 64 / 128), 256, 0, stream>>>(
        Xh, BT + (size_t)c0 * 64 * 96, Y, CC * 64);
    b23<96, 0><<<NF / 4, 256, 0, stream>>>(ans0, fc1, ftstart, fpk, fwtP,
                                           Y, nullptr, ans1, c0, CC, c == 0, c == S - 1);
  }
  // Stage 3
  cvt_f2b<<<(NF * 64 + 255) / 256, 256, 0, stream>>>(ans1, Xh, NF * 64);
  buildBT<<<(4096 * 64 + 255) / 256, 256, 0, stream>>>(W3, BT, 64);
  for (int c = 0; c < S; c++) {
    int c0 = c * CC;
    gemm_bf16<64><<<dim3(NF / 128, CC * 64 / 128), 256, 0, stream>>>(
        Xh, BT + (size_t)c0 * 64 * 64, Y, CC * 64);
    b23<64, 1><<<NF / 4, 256, 0, stream>>>(ans1, fc2, ftstart, fpk, fwtP,
                                           Y, ans1, ans2, c0, CC, c == 0, c == S - 1);
  }
  // Stage 4
  for (int c = 0; c < S; c++) {
    int c0 = c * CC;
    conv_k64_c2<<<dim3(NF * 2 / 256, CC), 256, 0, stream>>>(ans2, W4, Y4, c0, CC);
    b4_stage4<<<NF / 4, 256, 0, stream>>>(ans2, fc3, ftstart, fpk, fwtP,
                                          Y4, outpre, out, c0, CC, c == 0, c == S - 1);
  }
}

// Round 7
// 487.753 us; speedup vs baseline: 6.4522x; 1.0534x over previous
//
#include <hip/hip_runtime.h>

#define NF 16384
#define NB 4096
#define EF 262144
#define EB 65536
#define FBLK 1024   // EF/256
#define BBLK 256    // EB/256

typedef __attribute__((ext_vector_type(8))) short bf16x8;
typedef __attribute__((ext_vector_type(4))) float f32x4;

__device__ __forceinline__ short f2b(float f) {
  unsigned u = __float_as_uint(f);
  u += 0x7fff + ((u >> 16) & 1);   // RNE
  return (short)(u >> 16);
}
__device__ __forceinline__ unsigned pack2(float lo, float hi) {
  return (unsigned)(unsigned short)f2b(lo) | ((unsigned)(unsigned short)f2b(hi) << 16);
}
__device__ __forceinline__ float b2f_lo(unsigned u) {
  return __uint_as_float(u << 16);
}
__device__ __forceinline__ float b2f_hi(unsigned u) {
  return __uint_as_float(u & 0xffff0000u);
}

// ---------------------------------------------------------------------------
// Per-edge tent-basis cell + bilinear weights.
// ---------------------------------------------------------------------------
__global__ void __launch_bounds__(256) basis_kernel(
    const float* __restrict__ posT, const float* __restrict__ posS,
    const int* __restrict__ tgt, const int* __restrict__ src,
    const float* __restrict__ supportp, float sign,
    unsigned char* __restrict__ cells, float4* __restrict__ wts) {
  int e = blockIdx.x * 256 + threadIdx.x;
  float inv_sup = 1.0f / supportp[0];
  int ti = tgt[e], si = src[e];
  const float2* pT2 = (const float2*)posT;
  const float2* pS2 = (const float2*)posS;
  float2 pt = pT2[ti];
  float2 ps = pS2[si];
  // d = sign*(src-tgt)/support; sign=-1 fluid, +1 boundary. (-1)*(+0) = -0
  // preserves reference signed zeros for self-edges (atan2(-0,-0) = -pi).
  float dx = sign * ((ps.x - pt.x) * inv_sup);
  float dy = sign * ((ps.y - pt.y) * inv_sup);
  dx = fminf(fmaxf(dx, -1.f), 1.f);
  dy = fminf(fmaxf(dy, -1.f), 1.f);
  float r = sqrtf(dx * dx + dy * dy + 1e-12f);
  float theta;
  if (dx == 0.0f && dy == 0.0f) {
    float mag = __builtin_signbitf(dx) ? 3.14159265358979323846f : 0.0f;
    theta = __builtin_signbitf(dy) ? -mag : mag;
  } else {
    theta = atan2f(dy, dx);
  }
  float u = 2.f * r - 1.f;
  float v = theta * (1.f / 3.14159265358979323846f);
  float tu = (u + 1.f) * 3.5f;
  float tv = (v + 1.f) * 3.5f;
  int iu = min(max((int)floorf(tu), 0), 6);
  int iv = min(max((int)floorf(tv), 0), 6);
  float wu0 = fmaxf(0.f, 1.f - fabsf(tu - (float)iu));
  float wu1 = fmaxf(0.f, 1.f - fabsf(tu - (float)(iu + 1)));
  float wv0 = fmaxf(0.f, 1.f - fabsf(tv - (float)iv));
  float wv1 = fmaxf(0.f, 1.f - fabsf(tv - (float)(iv + 1)));
  cells[e] = (unsigned char)(iu * 8 + iv);
  wts[e] = make_float4(wu0 * wv0, wu0 * wv1, wu1 * wv0, wu1 * wv1);
}

// ---------------------------------------------------------------------------
// Target CSR build.
// ---------------------------------------------------------------------------
__global__ void __launch_bounds__(256) tgt_hist(const int* __restrict__ tgt, int n,
                                                int* __restrict__ hist) {
  int e = blockIdx.x * 256 + threadIdx.x;
  if (e < n) atomicAdd(hist + tgt[e], 1);
}

__global__ void __launch_bounds__(1024) csr_scan(const int* __restrict__ hist,
                                                 int* __restrict__ start,
                                                 int* __restrict__ cursor) {
  __shared__ int wtot[16];
  int t = threadIdx.x;
  int lane = t & 63, wv = t >> 6;
  int base = t * 16;
  int vals[16];
  int s = 0;
#pragma unroll
  for (int k = 0; k < 16; k++) { vals[k] = hist[base + k]; s += vals[k]; }
  int ss = s;
  for (int off = 1; off < 64; off <<= 1) {
    int o = __shfl_up(ss, off, 64);
    if (lane >= off) ss += o;
  }
  if (lane == 63) wtot[wv] = ss;
  __syncthreads();
  if (t < 16) {
    int v = wtot[t];
    int vv = v;
    for (int off = 1; off < 16; off <<= 1) {
      int o = __shfl_up(vv, off, 64);
      if (t >= off) vv += o;
    }
    wtot[t] = vv - v;
  }
  __syncthreads();
  int run = ss - s + wtot[wv];
#pragma unroll
  for (int k = 0; k < 16; k++) { start[base + k] = run; cursor[base + k] = run; run += vals[k]; }
  if (t == 1023) start[16384] = run;
}

__global__ void __launch_bounds__(256) tgt_scatter(const int* __restrict__ tgt, int n,
                                                   int* __restrict__ cursor,
                                                   int* __restrict__ edges) {
  int e = blockIdx.x * 256 + threadIdx.x;
  if (e < n) { int p = atomicAdd(cursor + tgt[e], 1); edges[p] = e; }
}

// Packed per-CSR-slot payload: (src | c00<<14) + float4 weights.
__global__ void __launch_bounds__(256) build_payload(
    const int* __restrict__ edges, const int* __restrict__ srcarr,
    const unsigned char* __restrict__ cells, const float4* __restrict__ wts, int n,
    unsigned* __restrict__ epk, float4* __restrict__ ewt) {
  int idx = blockIdx.x * 256 + threadIdx.x;
  if (idx < n) {
    int e = edges[idx];
    epk[idx] = (unsigned)srcarr[e] | ((unsigned)cells[e] << 14);
    ewt[idx] = wts[e];
  }
}

__global__ void __launch_bounds__(256) buildBT(const float* __restrict__ W,
                                               short* __restrict__ BT, int K) {
  int tid = blockIdx.x * 256 + threadIdx.x;
  if (tid >= 4096 * K) return;
  int k = tid % K, n = tid / K;
  BT[tid] = f2b(W[((size_t)(n >> 6) * K + k) * 64 + (n & 63)]);
}

// ---------------------------------------------------------------------------
// Dense MFMA GEMM (verified m89/m91 layout).
// ---------------------------------------------------------------------------
template <int K>
__global__ void __launch_bounds__(256, 2) gemm_bf16(
    const short* __restrict__ A, const short* __restrict__ BT,
    short* __restrict__ C, int N) {
  int lane = threadIdx.x & 63;
  int w = threadIdx.x >> 6;
  int m0 = blockIdx.x * 128 + (w & 1) * 64;
  int n0 = blockIdx.y * 128 + (w >> 1) * 64;
  int fr = lane & 15;
  int kg = lane >> 4;
  f32x4 acc[4][4] = {};
#pragma unroll
  for (int kc = 0; kc < K; kc += 32) {
    bf16x8 a[4], b[4];
#pragma unroll
    for (int i = 0; i < 4; i++) {
      a[i] = *(const bf16x8*)(A + (size_t)(m0 + i * 16 + fr) * K + kc + kg * 8);
      b[i] = *(const bf16x8*)(BT + (size_t)(n0 + i * 16 + fr) * K + kc + kg * 8);
    }
#pragma unroll
    for (int i = 0; i < 4; i++)
#pragma unroll
      for (int j = 0; j < 4; j++)
        acc[i][j] = __builtin_amdgcn_mfma_f32_16x16x32_bf16(a[i], b[j], acc[i][j], 0, 0, 0);
  }
#pragma unroll
  for (int i = 0; i < 4; i++) {
    int row = m0 + i * 16 + (lane >> 4) * 4;
#pragma unroll
    for (int j = 0; j < 4; j++) {
      int col = n0 + j * 16 + (lane & 15);
#pragma unroll
      for (int r = 0; r < 4; r++)
        C[(size_t)(row + r) * N + col] = f2b(acc[i][j][r]);
    }
  }
}

// ---------------------------------------------------------------------------
// Stage-4 dense conv (K=64, 2 couts/cell, fp32): wave per node, lane = cell,
// x-row broadcast via shuffles. Reads ans2 once; W4 L1-resident.
// ---------------------------------------------------------------------------
__global__ void __launch_bounds__(256) conv_k64_c2(
    const float* __restrict__ x, const float* __restrict__ W4 /*[64][64][2]*/,
    float* __restrict__ Y4, int c0, int CC) {
  int lane = threadIdx.x & 63;
  int n = blockIdx.x * 4 + (threadIdx.x >> 6);
  float xv = x[(size_t)n * 64 + lane];
  int cell = c0 + lane;
  const float2* wr = (const float2*)(W4 + (size_t)cell * 128);
  float a0 = 0.f, a1 = 0.f;
#pragma unroll
  for (int k = 0; k < 64; k++) {
    float xk = __shfl(xv, k, 64);
    float2 wk = wr[k];
    a0 = fmaf(xk, wk.x, a0);
    a1 = fmaf(xk, wk.y, a1);
  }
  if (lane < CC)
    *(float2*)(Y4 + (size_t)n * (CC * 2) + lane * 2) = make_float2(a0, a1);
}

// ---------------------------------------------------------------------------
// Stage 1, FULLY FUSED: per-edge K=4 conv computed on the fly (W0/W1 are
// L1-resident 32KB; x-row is a wave-uniform 16B broadcast). Single pass.
// Quarter q covers cell c00+{0,1,8,9}[q]; lane p = co-pair. Cross-quarter
// combine after the loops. Also emits bf16 ans0 (Xh96) for the stage-2 GEMM.
// ---------------------------------------------------------------------------
__global__ void __launch_bounds__(256, 4) b1_stage1(
    const float* __restrict__ ff, const float* __restrict__ bfe,
    const float* __restrict__ fc0,
    const float* __restrict__ W0, const float* __restrict__ W1,
    const int* __restrict__ ftstart, const unsigned* __restrict__ fpk,
    const float4* __restrict__ fwt,
    const int* __restrict__ btstart, const unsigned* __restrict__ bpk,
    const float4* __restrict__ bwt,
    float* __restrict__ ans0, short* __restrict__ Xh96) {
  int lane = threadIdx.x & 63;
  int t = blockIdx.x * 4 + (threadIdx.x >> 6);
  int q = lane >> 4;
  int p = lane & 15;
  int cofs = (q & 1) + (q >> 1) * 8;
  float2 fa = make_float2(0.f, 0.f);
  int s = ftstart[t], e1 = ftstart[t + 1];
  for (int idx = s; idx < e1; idx++) {
    unsigned pk = fpk[idx];
    float4 w4 = fwt[idx];
    int src = pk & 16383;
    int cell = (int)(pk >> 14) + cofs;
    float wq = (q == 0) ? w4.x : (q == 1) ? w4.y : (q == 2) ? w4.z : w4.w;
    float4 xv = *(const float4*)(ff + (size_t)src * 4);
    const float* Wc = W0 + cell * 128 + 2 * p;
    float2 k0 = *(const float2*)(Wc);
    float2 k1 = *(const float2*)(Wc + 32);
    float2 k2 = *(const float2*)(Wc + 64);
    float2 k3 = *(const float2*)(Wc + 96);
    float m0 = xv.x * k0.x + xv.y * k1.x + xv.z * k2.x + xv.w * k3.x;
    float m1 = xv.x * k0.y + xv.y * k1.y + xv.z * k2.y + xv.w * k3.y;
    fa.x = fmaf(wq, m0, fa.x);
    fa.y = fmaf(wq, m1, fa.y);
  }
  float2 ba = make_float2(0.f, 0.f);
  s = btstart[t]; e1 = btstart[t + 1];
  for (int idx = s; idx < e1; idx++) {
    unsigned pk = bpk[idx];
    float4 w4 = bwt[idx];
    int src = pk & 16383;
    int cell = (int)(pk >> 14) + cofs;
    float wq = (q == 0) ? w4.x : (q == 1) ? w4.y : (q == 2) ? w4.z : w4.w;
    float4 xv = *(const float4*)(bfe + (size_t)src * 4);
    const float* Wc = W1 + cell * 128 + 2 * p;
    float2 k0 = *(const float2*)(Wc);
    float2 k1 = *(const float2*)(Wc + 32);
    float2 k2 = *(const float2*)(Wc + 64);
    float2 k3 = *(const float2*)(Wc + 96);
    float m0 = xv.x * k0.x + xv.y * k1.x + xv.z * k2.x + xv.w * k3.x;
    float m1 = xv.x * k0.y + xv.y * k1.y + xv.z * k2.y + xv.w * k3.y;
    ba.x = fmaf(wq, m0, ba.x);
    ba.y = fmaf(wq, m1, ba.y);
  }
  fa.x += __shfl_xor(fa.x, 16, 64); fa.y += __shfl_xor(fa.y, 16, 64);
  fa.x += __shfl_xor(fa.x, 32, 64); fa.y += __shfl_xor(fa.y, 32, 64);
  ba.x += __shfl_xor(ba.x, 16, 64); ba.y += __shfl_xor(ba.y, 16, 64);
  ba.x += __shfl_xor(ba.x, 32, 64); ba.y += __shfl_xor(ba.y, 32, 64);
  if (lane < 16) {
    fa.x = fmaxf(fa.x, 0.f); fa.y = fmaxf(fa.y, 0.f);
    *(float2*)(ans0 + (size_t)t * 96 + 32 + 2 * p) = fa;
    *(unsigned*)(Xh96 + (size_t)t * 96 + 32 + 2 * p) = pack2(fa.x, fa.y);
  } else if (lane < 32) {
    ba.x = fmaxf(ba.x, 0.f); ba.y = fmaxf(ba.y, 0.f);
    *(float2*)(ans0 + (size_t)t * 96 + 64 + 2 * p) = ba;
    *(unsigned*)(Xh96 + (size_t)t * 96 + 64 + 2 * p) = pack2(ba.x, ba.y);
  } else if (lane < 48) {
    float4 fv = *(const float4*)(ff + (size_t)t * 4);
    float l0 = fv.x * fc0[2 * p] + fv.y * fc0[32 + 2 * p] +
               fv.z * fc0[64 + 2 * p] + fv.w * fc0[96 + 2 * p];
    float l1 = fv.x * fc0[2 * p + 1] + fv.y * fc0[32 + 2 * p + 1] +
               fv.z * fc0[64 + 2 * p + 1] + fv.w * fc0[96 + 2 * p + 1];
    l0 = fmaxf(l0, 0.f); l1 = fmaxf(l1, 0.f);
    *(float2*)(ans0 + (size_t)t * 96 + 2 * p) = make_float2(l0, l1);
    *(unsigned*)(Xh96 + (size_t)t * 96 + 2 * p) = pack2(l0, l1);
  }
}

// ---------------------------------------------------------------------------
// Phase B stages 2/3: quad-width Y gather + folded fc GEMM; 4-edge unroll.
// Optionally emits bf16 copy of dest (Xh64) for the next GEMM.
// ---------------------------------------------------------------------------
template <int CIN, int RESID, int WBF16>
__global__ void __launch_bounds__(256, 4) b23(
    const float* __restrict__ xin, const float* __restrict__ fc,
    const int* __restrict__ ftstart, const unsigned* __restrict__ epk,
    const float4* __restrict__ ewt, const short* __restrict__ Y,
    const float* __restrict__ resid, float* __restrict__ dest,
    short* __restrict__ Xh64, int c0, int CC, int init, int fin) {
  int lane = threadIdx.x & 63;
  int t = blockIdx.x * 4 + (threadIdx.x >> 6);
  int q = lane >> 4;
  int sub = lane & 15;
  int cofs = (q & 1) + (q >> 1) * 8;
  int YW = CC * 64;
  float a0 = 0.f, a1 = 0.f, a2 = 0.f, a3 = 0.f;
  if (init) {
    const float* xr = xin + (size_t)t * CIN;
#pragma unroll
    for (int kk = 0; kk < CIN / 4; kk++) {
      int k = q * (CIN / 4) + kk;
      float xv = xr[k];
      float4 fv = *(const float4*)(fc + (size_t)k * 64 + 4 * sub);
      a0 = fmaf(xv, fv.x, a0);
      a1 = fmaf(xv, fv.y, a1);
      a2 = fmaf(xv, fv.z, a2);
      a3 = fmaf(xv, fv.w, a3);
    }
  }
  int s = ftstart[t], e1 = ftstart[t + 1];
  int idx = s;
  for (; idx + 3 < e1; idx += 4) {
    unsigned pk_[4];
    float4 w_[4];
    int cell_[4], src_[4];
    float wq_[4];
    uint2 r_[4];
#pragma unroll
    for (int j = 0; j < 4; j++) {
      pk_[j] = epk[idx + j];
      w_[j] = ewt[idx + j];
      src_[j] = pk_[j] & 16383;
      cell_[j] = (int)(pk_[j] >> 14) + cofs - c0;
      wq_[j] = (q == 0) ? w_[j].x : (q == 1) ? w_[j].y : (q == 2) ? w_[j].z : w_[j].w;
      r_[j] = make_uint2(0, 0);
      if ((unsigned)cell_[j] < (unsigned)CC)
        r_[j] = *(const uint2*)(Y + (size_t)src_[j] * YW + cell_[j] * 64 + 4 * sub);
    }
#pragma unroll
    for (int j = 0; j < 4; j++) {
      a0 = fmaf(wq_[j], b2f_lo(r_[j].x), a0);
      a1 = fmaf(wq_[j], b2f_hi(r_[j].x), a1);
      a2 = fmaf(wq_[j], b2f_lo(r_[j].y), a2);
      a3 = fmaf(wq_[j], b2f_hi(r_[j].y), a3);
    }
  }
  for (; idx < e1; idx++) {
    unsigned pk = epk[idx];
    float4 w4 = ewt[idx];
    int src = pk & 16383;
    int cell = (int)(pk >> 14) + cofs - c0;
    float wq = (q == 0) ? w4.x : (q == 1) ? w4.y : (q == 2) ? w4.z : w4.w;
    if ((unsigned)cell < (unsigned)CC) {
      uint2 r = *(const uint2*)(Y + (size_t)src * YW + cell * 64 + 4 * sub);
      a0 = fmaf(wq, b2f_lo(r.x), a0);
      a1 = fmaf(wq, b2f_hi(r.x), a1);
      a2 = fmaf(wq, b2f_lo(r.y), a2);
      a3 = fmaf(wq, b2f_hi(r.y), a3);
    }
  }
  a0 += __shfl_xor(a0, 16, 64); a1 += __shfl_xor(a1, 16, 64);
  a2 += __shfl_xor(a2, 16, 64); a3 += __shfl_xor(a3, 16, 64);
  a0 += __shfl_xor(a0, 32, 64); a1 += __shfl_xor(a1, 32, 64);
  a2 += __shfl_xor(a2, 32, 64); a3 += __shfl_xor(a3, 32, 64);
  if (lane < 16) {
    float4* dst = (float4*)(dest + (size_t)t * 64 + 4 * sub);
    if (!init) {
      float4 d = *dst;
      a0 += d.x; a1 += d.y; a2 += d.z; a3 += d.w;
    }
    if (RESID && init) {
      float4 rd = *(const float4*)(resid + (size_t)t * 64 + 4 * sub);
      a0 += rd.x; a1 += rd.y; a2 += rd.z; a3 += rd.w;
    }
    if (fin) {
      a0 = fmaxf(a0, 0.f); a1 = fmaxf(a1, 0.f);
      a2 = fmaxf(a2, 0.f); a3 = fmaxf(a3, 0.f);
    }
    *dst = make_float4(a0, a1, a2, a3);
    if (WBF16 && fin) {
      uint2 pkd = make_uint2(pack2(a0, a1), pack2(a2, a3));
      *(uint2*)(Xh64 + (size_t)t * 64 + 4 * sub) = pkd;
    }
  }
}

// ---------------------------------------------------------------------------
// Phase B stage 4: out[t] = gather(Y4) + ans2@fc3.
// ---------------------------------------------------------------------------
__global__ void __launch_bounds__(256, 4) b4_stage4(
    const float* __restrict__ ans2, const float* __restrict__ fc3,
    const int* __restrict__ ftstart, const unsigned* __restrict__ epk,
    const float4* __restrict__ ewt, const float* __restrict__ Y4,
    float* __restrict__ partial, float* __restrict__ outp,
    int c0, int CC, int init, int fin) {
  int lane = threadIdx.x & 63;
  int t = blockIdx.x * 4 + (threadIdx.x >> 6);
  int s4 = ftstart[t] * 4, e4 = ftstart[t + 1] * 4;
  float m0 = 0.f, m1 = 0.f;
  for (int fq = s4 + lane; fq < e4; fq += 64) {
    int idx = fq >> 2, j = fq & 3;
    unsigned pk = epk[idx];
    float4 w4 = ewt[idx];
    int src = pk & 16383;
    int cell = (int)(pk >> 14) + (j & 1) + (j >> 1) * 8 - c0;
    float w = (j == 0) ? w4.x : (j == 1) ? w4.y : (j == 2) ? w4.z : w4.w;
    if ((unsigned)cell < (unsigned)CC) {
      float2 mm = *(const float2*)(Y4 + (size_t)src * (CC * 2) + cell * 2);
      m0 += w * mm.x;
      m1 += w * mm.y;
    }
  }
  if (init) {
    float a = ans2[(size_t)t * 64 + lane];
    m0 += a * fc3[lane * 2 + 0];
    m1 += a * fc3[lane * 2 + 1];
  }
#pragma unroll
  for (int off = 32; off > 0; off >>= 1) {
    m0 += __shfl_xor(m0, off, 64);
    m1 += __shfl_xor(m1, off, 64);
  }
  if (lane == 0) {
    if (!init) { m0 += partial[t * 2]; m1 += partial[t * 2 + 1]; }
    if (fin) { outp[t * 2] = m0; outp[t * 2 + 1] = m1; }
    else { partial[t * 2] = m0; partial[t * 2 + 1] = m1; }
  }
}

// ---------------------------------------------------------------------------
extern "C" void kernel_launch(void* const* d_in, const int* in_sizes, int n_in,
                              void* d_out, int out_size, void* d_ws, size_t ws_size,
                              hipStream_t stream) {
  const float* fp  = (const float*)d_in[0];
  const float* bp  = (const float*)d_in[1];
  const float* ff  = (const float*)d_in[2];
  const float* bfe = (const float*)d_in[3];
  const float* sup = (const float*)d_in[4];
  const int* fi  = (const int*)d_in[5];
  const int* fj  = (const int*)d_in[6];
  const int* bfi = (const int*)d_in[7];
  const int* bb  = (const int*)d_in[8];
  const float* W0 = (const float*)d_in[9];
  const float* W1 = (const float*)d_in[10];
  const float* W2 = (const float*)d_in[11];
  const float* W3 = (const float*)d_in[12];
  const float* W4 = (const float*)d_in[13];
  const float* fc0 = (const float*)d_in[14];
  const float* fc1 = (const float*)d_in[15];
  const float* fc2 = (const float*)d_in[16];
  const float* fc3 = (const float*)d_in[17];
  float* out = (float*)d_out;

  char* w = (char*)d_ws;
  size_t off = 0;
  auto alloc = [&](size_t bytes) {
    char* p = w + off;
    off += (bytes + 255) & ~size_t(255);
    return p;
  };
  float* ans0   = (float*)alloc((size_t)NF * 96 * 4);
  float* ans1   = (float*)alloc((size_t)NF * 64 * 4);
  float* ans2   = (float*)alloc((size_t)NF * 64 * 4);
  float* outpre = (float*)alloc((size_t)NF * 2 * 4);
  unsigned char* fcells = (unsigned char*)alloc((size_t)EF);
  float4* fwts   = (float4*)alloc((size_t)EF * 16);
  unsigned char* bcells = (unsigned char*)alloc((size_t)EB);
  float4* bwts   = (float4*)alloc((size_t)EB * 16);
  int* fthist  = (int*)alloc((size_t)NF * 4);
  int* ftstart = (int*)alloc((size_t)(NF + 1) * 4);
  int* ftcur   = (int*)alloc((size_t)NF * 4);
  int* ftedges = (int*)alloc((size_t)EF * 4);
  int* bthist  = (int*)alloc((size_t)NF * 4);
  int* btstart = (int*)alloc((size_t)(NF + 1) * 4);
  int* btcur   = (int*)alloc((size_t)NF * 4);
  int* btedges = (int*)alloc((size_t)EB * 4);
  unsigned* fpk  = (unsigned*)alloc((size_t)EF * 4);
  float4* fwtP   = (float4*)alloc((size_t)EF * 16);
  unsigned* bpk  = (unsigned*)alloc((size_t)EB * 4);
  float4* bwtP   = (float4*)alloc((size_t)EB * 16);
  short* Xh96 = (short*)alloc((size_t)NF * 96 * 2);
  short* Xh64 = (short*)alloc((size_t)NF * 64 * 2);
  short* BT = (short*)alloc((size_t)4096 * 96 * 2);
  char* Yreg = w + off;
  size_t avail = (ws_size > off) ? (ws_size - off) : 0;
  size_t percell = (size_t)NF * 64 * 2;
  int CC = 64;
  while (CC > 8 && (size_t)CC * percell > avail) CC >>= 1;
  int S = 64 / CC;
  short* Y  = (short*)Yreg;
  float* Y4 = (float*)Yreg;

  hipMemsetAsync(fthist, 0, (size_t)NF * 4, stream);
  hipMemsetAsync(bthist, 0, (size_t)NF * 4, stream);

  basis_kernel<<<FBLK, 256, 0, stream>>>(fp, fp, fi, fj, sup, -1.f, fcells, fwts);
  basis_kernel<<<BBLK, 256, 0, stream>>>(fp, bp, bfi, bb, sup, 1.f, bcells, bwts);
  tgt_hist<<<FBLK, 256, 0, stream>>>(fi, EF, fthist);
  tgt_hist<<<BBLK, 256, 0, stream>>>(bfi, EB, bthist);
  csr_scan<<<1, 1024, 0, stream>>>(fthist, ftstart, ftcur);
  csr_scan<<<1, 1024, 0, stream>>>(bthist, btstart, btcur);
  tgt_scatter<<<FBLK, 256, 0, stream>>>(fi, EF, ftcur, ftedges);
  tgt_scatter<<<BBLK, 256, 0, stream>>>(bfi, EB, btcur, btedges);
  build_payload<<<FBLK, 256, 0, stream>>>(ftedges, fj, fcells, fwts, EF, fpk, fwtP);
  build_payload<<<BBLK, 256, 0, stream>>>(btedges, bb, bcells, bwts, EB, bpk, bwtP);

  // Stage 1: fully fused, single pass. Emits ans0 + bf16 Xh96.
  b1_stage1<<<NF / 4, 256, 0, stream>>>(ff, bfe, fc0, W0, W1,
                                        ftstart, fpk, fwtP, btstart, bpk, bwtP,
                                        ans0, Xh96);
  // Stage 2: MFMA GEMM + gather. Emits ans1 + bf16 Xh64.
  buildBT<<<(4096 * 96 + 255) / 256, 256, 0, stream>>>(W2, BT, 96);
  for (int c = 0; c < S; c++) {
    int c0 = c * CC;
    gemm_bf16<96><<<dim3(NF / 128, CC * 64 / 128), 256, 0, stream>>>(
        Xh96, BT + (size_t)c0 * 64 * 96, Y, CC * 64);
    b23<96, 0, 1><<<NF / 4, 256, 0, stream>>>(ans0, fc1, ftstart, fpk, fwtP,
                                              Y, nullptr, ans1, Xh64,
                                              c0, CC, c == 0, c == S - 1);
  }
  // Stage 3
  buildBT<<<(4096 * 64 + 255) / 256, 256, 0, stream>>>(W3, BT, 64);
  for (int c = 0; c < S; c++) {
    int c0 = c * CC;
    gemm_bf16<64><<<dim3(NF / 128, CC * 64 / 128), 256, 0, stream>>>(
        Xh64, BT + (size_t)c0 * 64 * 64, Y, CC * 64);
    b23<64, 1, 0><<<NF / 4, 256, 0, stream>>>(ans1, fc2, ftstart, fpk, fwtP,
                                              Y, ans1, ans2, nullptr,
                                              c0, CC, c == 0, c == S - 1);
  }
  // Stage 4
  for (int c = 0; c < S; c++) {
    int c0 = c * CC;
    conv_k64_c2<<<NF / 4, 256, 0, stream>>>(ans2, W4, Y4, c0, CC);
    b4_stage4<<<NF / 4, 256, 0, stream>>>(ans2, fc3, ftstart, fpk, fwtP,
                                          Y4, outpre, out, c0, CC, c == 0, c == S - 1);
  }
}

// Round 8
// 464.803 us; speedup vs baseline: 6.7708x; 1.0494x over previous
//
#include <hip/hip_runtime.h>

#define NF 16384
#define NB 4096
#define EF 262144
#define EB 65536
#define FBLK 1024   // EF/256
#define BBLK 256    // EB/256

typedef __attribute__((ext_vector_type(8))) short bf16x8;
typedef __attribute__((ext_vector_type(4))) float f32x4;

__device__ __forceinline__ short f2b(float f) {
  unsigned u = __float_as_uint(f);
  u += 0x7fff + ((u >> 16) & 1);   // RNE
  return (short)(u >> 16);
}
__device__ __forceinline__ unsigned pack2(float lo, float hi) {
  return (unsigned)(unsigned short)f2b(lo) | ((unsigned)(unsigned short)f2b(hi) << 16);
}
__device__ __forceinline__ float b2f_lo(unsigned u) {
  return __uint_as_float(u << 16);
}
__device__ __forceinline__ float b2f_hi(unsigned u) {
  return __uint_as_float(u & 0xffff0000u);
}

// ---------------------------------------------------------------------------
// Target CSR build (fluid + boundary merged per launch).
// ---------------------------------------------------------------------------
__global__ void __launch_bounds__(256) dual_hist(const int* __restrict__ fi,
                                                 const int* __restrict__ bfi,
                                                 int* __restrict__ fhist,
                                                 int* __restrict__ bhist) {
  int bid = blockIdx.x;
  if (bid < FBLK) {
    int e = bid * 256 + threadIdx.x;
    atomicAdd(fhist + fi[e], 1);
  } else {
    int e = (bid - FBLK) * 256 + threadIdx.x;
    atomicAdd(bhist + bfi[e], 1);
  }
}

__global__ void __launch_bounds__(1024) csr_scan2(const int* __restrict__ fhist,
                                                  const int* __restrict__ bhist,
                                                  int* __restrict__ fstart, int* __restrict__ fcur,
                                                  int* __restrict__ bstart, int* __restrict__ bcur) {
  const int* hist = blockIdx.x ? bhist : fhist;
  int* start = blockIdx.x ? bstart : fstart;
  int* cursor = blockIdx.x ? bcur : fcur;
  __shared__ int wtot[16];
  int t = threadIdx.x;
  int lane = t & 63, wv = t >> 6;
  int base = t * 16;
  int vals[16];
  int s = 0;
#pragma unroll
  for (int k = 0; k < 16; k++) { vals[k] = hist[base + k]; s += vals[k]; }
  int ss = s;
  for (int off = 1; off < 64; off <<= 1) {
    int o = __shfl_up(ss, off, 64);
    if (lane >= off) ss += o;
  }
  if (lane == 63) wtot[wv] = ss;
  __syncthreads();
  if (t < 16) {
    int v = wtot[t];
    int vv = v;
    for (int off = 1; off < 16; off <<= 1) {
      int o = __shfl_up(vv, off, 64);
      if (t >= off) vv += o;
    }
    wtot[t] = vv - v;
  }
  __syncthreads();
  int run = ss - s + wtot[wv];
#pragma unroll
  for (int k = 0; k < 16; k++) { start[base + k] = run; cursor[base + k] = run; run += vals[k]; }
  if (t == 1023) start[16384] = run;
}

__global__ void __launch_bounds__(256) dual_scatter(const int* __restrict__ fi,
                                                    const int* __restrict__ bfi,
                                                    int* __restrict__ fcur, int* __restrict__ bcur,
                                                    int* __restrict__ fedges, int* __restrict__ bedges) {
  int bid = blockIdx.x;
  if (bid < FBLK) {
    int e = bid * 256 + threadIdx.x;
    int p = atomicAdd(fcur + fi[e], 1);
    fedges[p] = e;
  } else {
    int e = (bid - FBLK) * 256 + threadIdx.x;
    int p = atomicAdd(bcur + bfi[e], 1);
    bedges[p] = e;
  }
}

// ---------------------------------------------------------------------------
// Payload build WITH fused tent-basis math: per CSR slot, read edge, compute
// polar map + bilinear cell weights, emit packed (src|c00<<14) + float4 w.
// ---------------------------------------------------------------------------
__global__ void __launch_bounds__(256) dual_payload_basis(
    const int* __restrict__ fedges, const int* __restrict__ bedges,
    const int* __restrict__ fi, const int* __restrict__ fj,
    const int* __restrict__ bfi, const int* __restrict__ bb,
    const float* __restrict__ fp, const float* __restrict__ bp,
    const float* __restrict__ supportp,
    unsigned* __restrict__ fpk, float4* __restrict__ fwt,
    unsigned* __restrict__ bpk, float4* __restrict__ bwt) {
  int bid = blockIdx.x;
  bool fluid = bid < FBLK;
  int idx = (fluid ? bid : bid - FBLK) * 256 + threadIdx.x;
  int e = fluid ? fedges[idx] : bedges[idx];
  int ti = fluid ? fi[e] : bfi[e];
  int si = fluid ? fj[e] : bb[e];
  const float2* pT2 = (const float2*)fp;
  const float2* pS2 = fluid ? (const float2*)fp : (const float2*)bp;
  float sign = fluid ? -1.f : 1.f;
  float inv_sup = 1.0f / supportp[0];
  float2 pt = pT2[ti];
  float2 ps = pS2[si];
  // d = sign*(src-tgt)/support. (-1)*(+0) = -0 preserves reference signed
  // zeros for self-edges (atan2(-0,-0) = -pi).
  float dx = sign * ((ps.x - pt.x) * inv_sup);
  float dy = sign * ((ps.y - pt.y) * inv_sup);
  dx = fminf(fmaxf(dx, -1.f), 1.f);
  dy = fminf(fmaxf(dy, -1.f), 1.f);
  float r = sqrtf(dx * dx + dy * dy + 1e-12f);
  float theta;
  if (dx == 0.0f && dy == 0.0f) {
    float mag = __builtin_signbitf(dx) ? 3.14159265358979323846f : 0.0f;
    theta = __builtin_signbitf(dy) ? -mag : mag;
  } else {
    theta = atan2f(dy, dx);
  }
  float u = 2.f * r - 1.f;
  float v = theta * (1.f / 3.14159265358979323846f);
  float tu = (u + 1.f) * 3.5f;
  float tv = (v + 1.f) * 3.5f;
  int iu = min(max((int)floorf(tu), 0), 6);
  int iv = min(max((int)floorf(tv), 0), 6);
  float wu0 = fmaxf(0.f, 1.f - fabsf(tu - (float)iu));
  float wu1 = fmaxf(0.f, 1.f - fabsf(tu - (float)(iu + 1)));
  float wv0 = fmaxf(0.f, 1.f - fabsf(tv - (float)iv));
  float wv1 = fmaxf(0.f, 1.f - fabsf(tv - (float)(iv + 1)));
  unsigned pk = (unsigned)si | ((unsigned)(iu * 8 + iv) << 14);
  float4 w4 = make_float4(wu0 * wv0, wu0 * wv1, wu1 * wv0, wu1 * wv1);
  if (fluid) { fpk[idx] = pk; fwt[idx] = w4; }
  else       { bpk[idx] = pk; bwt[idx] = w4; }
}

__global__ void __launch_bounds__(256) buildBT(const float* __restrict__ W,
                                               short* __restrict__ BT, int K) {
  int tid = blockIdx.x * 256 + threadIdx.x;
  if (tid >= 4096 * K) return;
  int k = tid % K, n = tid / K;
  BT[tid] = f2b(W[((size_t)(n >> 6) * K + k) * 64 + (n & 63)]);
}

// ---------------------------------------------------------------------------
// Dense MFMA GEMM (verified m89/m91 layout).
// ---------------------------------------------------------------------------
template <int K>
__global__ void __launch_bounds__(256, 2) gemm_bf16(
    const short* __restrict__ A, const short* __restrict__ BT,
    short* __restrict__ C, int N) {
  int lane = threadIdx.x & 63;
  int w = threadIdx.x >> 6;
  int m0 = blockIdx.x * 128 + (w & 1) * 64;
  int n0 = blockIdx.y * 128 + (w >> 1) * 64;
  int fr = lane & 15;
  int kg = lane >> 4;
  f32x4 acc[4][4] = {};
#pragma unroll
  for (int kc = 0; kc < K; kc += 32) {
    bf16x8 a[4], b[4];
#pragma unroll
    for (int i = 0; i < 4; i++) {
      a[i] = *(const bf16x8*)(A + (size_t)(m0 + i * 16 + fr) * K + kc + kg * 8);
      b[i] = *(const bf16x8*)(BT + (size_t)(n0 + i * 16 + fr) * K + kc + kg * 8);
    }
#pragma unroll
    for (int i = 0; i < 4; i++)
#pragma unroll
      for (int j = 0; j < 4; j++)
        acc[i][j] = __builtin_amdgcn_mfma_f32_16x16x32_bf16(a[i], b[j], acc[i][j], 0, 0, 0);
  }
#pragma unroll
  for (int i = 0; i < 4; i++) {
    int row = m0 + i * 16 + (lane >> 4) * 4;
#pragma unroll
    for (int j = 0; j < 4; j++) {
      int col = n0 + j * 16 + (lane & 15);
#pragma unroll
      for (int r = 0; r < 4; r++)
        C[(size_t)(row + r) * N + col] = f2b(acc[i][j][r]);
    }
  }
}

// ---------------------------------------------------------------------------
// Stage-4 dense conv (K=64, 2 couts/cell, fp32): wave per node, lane = cell.
// ---------------------------------------------------------------------------
__global__ void __launch_bounds__(256) conv_k64_c2(
    const float* __restrict__ x, const float* __restrict__ W4 /*[64][64][2]*/,
    float* __restrict__ Y4, int c0, int CC) {
  int lane = threadIdx.x & 63;
  int n = blockIdx.x * 4 + (threadIdx.x >> 6);
  float xv = x[(size_t)n * 64 + lane];
  int cell = c0 + lane;
  const float2* wr = (const float2*)(W4 + (size_t)cell * 128);
  float a0 = 0.f, a1 = 0.f;
#pragma unroll
  for (int k = 0; k < 64; k++) {
    float xk = __shfl(xv, k, 64);
    float2 wk = wr[k];
    a0 = fmaf(xk, wk.x, a0);
    a1 = fmaf(xk, wk.y, a1);
  }
  if (lane < CC)
    *(float2*)(Y4 + (size_t)n * (CC * 2) + lane * 2) = make_float2(a0, a1);
}

// ---------------------------------------------------------------------------
// Stage 1, fully fused + 4-edge unroll for memory-level parallelism.
// ---------------------------------------------------------------------------
__global__ void __launch_bounds__(256, 4) b1_stage1(
    const float* __restrict__ ff, const float* __restrict__ bfe,
    const float* __restrict__ fc0,
    const float* __restrict__ W0, const float* __restrict__ W1,
    const int* __restrict__ ftstart, const unsigned* __restrict__ fpk,
    const float4* __restrict__ fwt,
    const int* __restrict__ btstart, const unsigned* __restrict__ bpk,
    const float4* __restrict__ bwt,
    float* __restrict__ ans0, short* __restrict__ Xh96) {
  int lane = threadIdx.x & 63;
  int t = blockIdx.x * 4 + (threadIdx.x >> 6);
  int q = lane >> 4;
  int p = lane & 15;
  int cofs = (q & 1) + (q >> 1) * 8;

  auto edge = [&](unsigned pk, float4 w4, float4 xv, const float* W, float2& acc) {
    int cell = (int)(pk >> 14) + cofs;
    float wq = (q == 0) ? w4.x : (q == 1) ? w4.y : (q == 2) ? w4.z : w4.w;
    const float* Wc = W + cell * 128 + 2 * p;
    float2 k0 = *(const float2*)(Wc);
    float2 k1 = *(const float2*)(Wc + 32);
    float2 k2 = *(const float2*)(Wc + 64);
    float2 k3 = *(const float2*)(Wc + 96);
    float m0 = xv.x * k0.x + xv.y * k1.x + xv.z * k2.x + xv.w * k3.x;
    float m1 = xv.x * k0.y + xv.y * k1.y + xv.z * k2.y + xv.w * k3.y;
    acc.x = fmaf(wq, m0, acc.x);
    acc.y = fmaf(wq, m1, acc.y);
  };

  float2 fa = make_float2(0.f, 0.f);
  int s = ftstart[t], e1 = ftstart[t + 1];
  int idx = s;
  for (; idx + 3 < e1; idx += 4) {
    unsigned pk0 = fpk[idx], pk1 = fpk[idx + 1], pk2 = fpk[idx + 2], pk3 = fpk[idx + 3];
    float4 w0 = fwt[idx], w1 = fwt[idx + 1], w2 = fwt[idx + 2], w3 = fwt[idx + 3];
    float4 x0 = *(const float4*)(ff + (size_t)(pk0 & 16383) * 4);
    float4 x1 = *(const float4*)(ff + (size_t)(pk1 & 16383) * 4);
    float4 x2 = *(const float4*)(ff + (size_t)(pk2 & 16383) * 4);
    float4 x3 = *(const float4*)(ff + (size_t)(pk3 & 16383) * 4);
    edge(pk0, w0, x0, W0, fa);
    edge(pk1, w1, x1, W0, fa);
    edge(pk2, w2, x2, W0, fa);
    edge(pk3, w3, x3, W0, fa);
  }
  for (; idx < e1; idx++) {
    unsigned pk = fpk[idx];
    float4 w4 = fwt[idx];
    float4 xv = *(const float4*)(ff + (size_t)(pk & 16383) * 4);
    edge(pk, w4, xv, W0, fa);
  }
  float2 ba = make_float2(0.f, 0.f);
  s = btstart[t]; e1 = btstart[t + 1];
  idx = s;
  for (; idx + 3 < e1; idx += 4) {
    unsigned pk0 = bpk[idx], pk1 = bpk[idx + 1], pk2 = bpk[idx + 2], pk3 = bpk[idx + 3];
    float4 w0 = bwt[idx], w1 = bwt[idx + 1], w2 = bwt[idx + 2], w3 = bwt[idx + 3];
    float4 x0 = *(const float4*)(bfe + (size_t)(pk0 & 16383) * 4);
    float4 x1 = *(const float4*)(bfe + (size_t)(pk1 & 16383) * 4);
    float4 x2 = *(const float4*)(bfe + (size_t)(pk2 & 16383) * 4);
    float4 x3 = *(const float4*)(bfe + (size_t)(pk3 & 16383) * 4);
    edge(pk0, w0, x0, W1, ba);
    edge(pk1, w1, x1, W1, ba);
    edge(pk2, w2, x2, W1, ba);
    edge(pk3, w3, x3, W1, ba);
  }
  for (; idx < e1; idx++) {
    unsigned pk = bpk[idx];
    float4 w4 = bwt[idx];
    float4 xv = *(const float4*)(bfe + (size_t)(pk & 16383) * 4);
    edge(pk, w4, xv, W1, ba);
  }
  fa.x += __shfl_xor(fa.x, 16, 64); fa.y += __shfl_xor(fa.y, 16, 64);
  fa.x += __shfl_xor(fa.x, 32, 64); fa.y += __shfl_xor(fa.y, 32, 64);
  ba.x += __shfl_xor(ba.x, 16, 64); ba.y += __shfl_xor(ba.y, 16, 64);
  ba.x += __shfl_xor(ba.x, 32, 64); ba.y += __shfl_xor(ba.y, 32, 64);
  if (lane < 16) {
    fa.x = fmaxf(fa.x, 0.f); fa.y = fmaxf(fa.y, 0.f);
    *(float2*)(ans0 + (size_t)t * 96 + 32 + 2 * p) = fa;
    *(unsigned*)(Xh96 + (size_t)t * 96 + 32 + 2 * p) = pack2(fa.x, fa.y);
  } else if (lane < 32) {
    ba.x = fmaxf(ba.x, 0.f); ba.y = fmaxf(ba.y, 0.f);
    *(float2*)(ans0 + (size_t)t * 96 + 64 + 2 * p) = ba;
    *(unsigned*)(Xh96 + (size_t)t * 96 + 64 + 2 * p) = pack2(ba.x, ba.y);
  } else if (lane < 48) {
    float4 fv = *(const float4*)(ff + (size_t)t * 4);
    float l0 = fv.x * fc0[2 * p] + fv.y * fc0[32 + 2 * p] +
               fv.z * fc0[64 + 2 * p] + fv.w * fc0[96 + 2 * p];
    float l1 = fv.x * fc0[2 * p + 1] + fv.y * fc0[32 + 2 * p + 1] +
               fv.z * fc0[64 + 2 * p + 1] + fv.w * fc0[96 + 2 * p + 1];
    l0 = fmaxf(l0, 0.f); l1 = fmaxf(l1, 0.f);
    *(float2*)(ans0 + (size_t)t * 96 + 2 * p) = make_float2(l0, l1);
    *(unsigned*)(Xh96 + (size_t)t * 96 + 2 * p) = pack2(l0, l1);
  }
}

// ---------------------------------------------------------------------------
// Phase B stages 2/3: quad-width Y gather + folded fc GEMM; 4-edge unroll.
// ---------------------------------------------------------------------------
template <int CIN, int RESID, int WBF16>
__global__ void __launch_bounds__(256, 4) b23(
    const float* __restrict__ xin, const float* __restrict__ fc,
    const int* __restrict__ ftstart, const unsigned* __restrict__ epk,
    const float4* __restrict__ ewt, const short* __restrict__ Y,
    const float* __restrict__ resid, float* __restrict__ dest,
    short* __restrict__ Xh64, int c0, int CC, int init, int fin) {
  int lane = threadIdx.x & 63;
  int t = blockIdx.x * 4 + (threadIdx.x >> 6);
  int q = lane >> 4;
  int sub = lane & 15;
  int cofs = (q & 1) + (q >> 1) * 8;
  int YW = CC * 64;
  float a0 = 0.f, a1 = 0.f, a2 = 0.f, a3 = 0.f;
  if (init) {
    const float* xr = xin + (size_t)t * CIN;
#pragma unroll
    for (int kk = 0; kk < CIN / 4; kk++) {
      int k = q * (CIN / 4) + kk;
      float xv = xr[k];
      float4 fv = *(const float4*)(fc + (size_t)k * 64 + 4 * sub);
      a0 = fmaf(xv, fv.x, a0);
      a1 = fmaf(xv, fv.y, a1);
      a2 = fmaf(xv, fv.z, a2);
      a3 = fmaf(xv, fv.w, a3);
    }
  }
  int s = ftstart[t], e1 = ftstart[t + 1];
  int idx = s;
  for (; idx + 3 < e1; idx += 4) {
    unsigned pk_[4];
    float4 w_[4];
    int cell_[4], src_[4];
    float wq_[4];
    uint2 r_[4];
#pragma unroll
    for (int j = 0; j < 4; j++) {
      pk_[j] = epk[idx + j];
      w_[j] = ewt[idx + j];
      src_[j] = pk_[j] & 16383;
      cell_[j] = (int)(pk_[j] >> 14) + cofs - c0;
      wq_[j] = (q == 0) ? w_[j].x : (q == 1) ? w_[j].y : (q == 2) ? w_[j].z : w_[j].w;
      r_[j] = make_uint2(0, 0);
      if ((unsigned)cell_[j] < (unsigned)CC)
        r_[j] = *(const uint2*)(Y + (size_t)src_[j] * YW + cell_[j] * 64 + 4 * sub);
    }
#pragma unroll
    for (int j = 0; j < 4; j++) {
      a0 = fmaf(wq_[j], b2f_lo(r_[j].x), a0);
      a1 = fmaf(wq_[j], b2f_hi(r_[j].x), a1);
      a2 = fmaf(wq_[j], b2f_lo(r_[j].y), a2);
      a3 = fmaf(wq_[j], b2f_hi(r_[j].y), a3);
    }
  }
  for (; idx < e1; idx++) {
    unsigned pk = epk[idx];
    float4 w4 = ewt[idx];
    int src = pk & 16383;
    int cell = (int)(pk >> 14) + cofs - c0;
    float wq = (q == 0) ? w4.x : (q == 1) ? w4.y : (q == 2) ? w4.z : w4.w;
    if ((unsigned)cell < (unsigned)CC) {
      uint2 r = *(const uint2*)(Y + (size_t)src * YW + cell * 64 + 4 * sub);
      a0 = fmaf(wq, b2f_lo(r.x), a0);
      a1 = fmaf(wq, b2f_hi(r.x), a1);
      a2 = fmaf(wq, b2f_lo(r.y), a2);
      a3 = fmaf(wq, b2f_hi(r.y), a3);
    }
  }
  a0 += __shfl_xor(a0, 16, 64); a1 += __shfl_xor(a1, 16, 64);
  a2 += __shfl_xor(a2, 16, 64); a3 += __shfl_xor(a3, 16, 64);
  a0 += __shfl_xor(a0, 32, 64); a1 += __shfl_xor(a1, 32, 64);
  a2 += __shfl_xor(a2, 32, 64); a3 += __shfl_xor(a3, 32, 64);
  if (lane < 16) {
    float4* dst = (float4*)(dest + (size_t)t * 64 + 4 * sub);
    if (!init) {
      float4 d = *dst;
      a0 += d.x; a1 += d.y; a2 += d.z; a3 += d.w;
    }
    if (RESID && init) {
      float4 rd = *(const float4*)(resid + (size_t)t * 64 + 4 * sub);
      a0 += rd.x; a1 += rd.y; a2 += rd.z; a3 += rd.w;
    }
    if (fin) {
      a0 = fmaxf(a0, 0.f); a1 = fmaxf(a1, 0.f);
      a2 = fmaxf(a2, 0.f); a3 = fmaxf(a3, 0.f);
    }
    *dst = make_float4(a0, a1, a2, a3);
    if (WBF16 && fin) {
      uint2 pkd = make_uint2(pack2(a0, a1), pack2(a2, a3));
      *(uint2*)(Xh64 + (size_t)t * 64 + 4 * sub) = pkd;
    }
  }
}

// ---------------------------------------------------------------------------
// Phase B stage 4: out[t] = gather(Y4) + ans2@fc3.
// ---------------------------------------------------------------------------
__global__ void __launch_bounds__(256, 4) b4_stage4(
    const float* __restrict__ ans2, const float* __restrict__ fc3,
    const int* __restrict__ ftstart, const unsigned* __restrict__ epk,
    const float4* __restrict__ ewt, const float* __restrict__ Y4,
    float* __restrict__ partial, float* __restrict__ outp,
    int c0, int CC, int init, int fin) {
  int lane = threadIdx.x & 63;
  int t = blockIdx.x * 4 + (threadIdx.x >> 6);
  int s4 = ftstart[t] * 4, e4 = ftstart[t + 1] * 4;
  float m0 = 0.f, m1 = 0.f;
  for (int fq = s4 + lane; fq < e4; fq += 64) {
    int idx = fq >> 2, j = fq & 3;
    unsigned pk = epk[idx];
    float4 w4 = ewt[idx];
    int src = pk & 16383;
    int cell = (int)(pk >> 14) + (j & 1) + (j >> 1) * 8 - c0;
    float w = (j == 0) ? w4.x : (j == 1) ? w4.y : (j == 2) ? w4.z : w4.w;
    if ((unsigned)cell < (unsigned)CC) {
      float2 mm = *(const float2*)(Y4 + (size_t)src * (CC * 2) + cell * 2);
      m0 += w * mm.x;
      m1 += w * mm.y;
    }
  }
  if (init) {
    float a = ans2[(size_t)t * 64 + lane];
    m0 += a * fc3[lane * 2 + 0];
    m1 += a * fc3[lane * 2 + 1];
  }
#pragma unroll
  for (int off = 32; off > 0; off >>= 1) {
    m0 += __shfl_xor(m0, off, 64);
    m1 += __shfl_xor(m1, off, 64);
  }
  if (lane == 0) {
    if (!init) { m0 += partial[t * 2]; m1 += partial[t * 2 + 1]; }
    if (fin) { outp[t * 2] = m0; outp[t * 2 + 1] = m1; }
    else { partial[t * 2] = m0; partial[t * 2 + 1] = m1; }
  }
}

// ---------------------------------------------------------------------------
extern "C" void kernel_launch(void* const* d_in, const int* in_sizes, int n_in,
                              void* d_out, int out_size, void* d_ws, size_t ws_size,
                              hipStream_t stream) {
  const float* fp  = (const float*)d_in[0];
  const float* bp  = (const float*)d_in[1];
  const float* ff  = (const float*)d_in[2];
  const float* bfe = (const float*)d_in[3];
  const float* sup = (const float*)d_in[4];
  const int* fi  = (const int*)d_in[5];
  const int* fj  = (const int*)d_in[6];
  const int* bfi = (const int*)d_in[7];
  const int* bb  = (const int*)d_in[8];
  const float* W0 = (const float*)d_in[9];
  const float* W1 = (const float*)d_in[10];
  const float* W2 = (const float*)d_in[11];
  const float* W3 = (const float*)d_in[12];
  const float* W4 = (const float*)d_in[13];
  const float* fc0 = (const float*)d_in[14];
  const float* fc1 = (const float*)d_in[15];
  const float* fc2 = (const float*)d_in[16];
  const float* fc3 = (const float*)d_in[17];
  float* out = (float*)d_out;

  char* w = (char*)d_ws;
  size_t off = 0;
  auto alloc = [&](size_t bytes) {
    char* p = w + off;
    off += (bytes + 255) & ~size_t(255);
    return p;
  };
  float* ans0   = (float*)alloc((size_t)NF * 96 * 4);
  float* ans1   = (float*)alloc((size_t)NF * 64 * 4);
  float* ans2   = (float*)alloc((size_t)NF * 64 * 4);
  float* outpre = (float*)alloc((size_t)NF * 2 * 4);
  int* fthist  = (int*)alloc((size_t)NF * 4);
  int* bthist  = (int*)alloc((size_t)NF * 4);   // adjacent to fthist: one memset
  int* ftstart = (int*)alloc((size_t)(NF + 1) * 4);
  int* ftcur   = (int*)alloc((size_t)NF * 4);
  int* ftedges = (int*)alloc((size_t)EF * 4);
  int* btstart = (int*)alloc((size_t)(NF + 1) * 4);
  int* btcur   = (int*)alloc((size_t)NF * 4);
  int* btedges = (int*)alloc((size_t)EB * 4);
  unsigned* fpk  = (unsigned*)alloc((size_t)EF * 4);
  float4* fwtP   = (float4*)alloc((size_t)EF * 16);
  unsigned* bpk  = (unsigned*)alloc((size_t)EB * 4);
  float4* bwtP   = (float4*)alloc((size_t)EB * 16);
  short* Xh96 = (short*)alloc((size_t)NF * 96 * 2);
  short* Xh64 = (short*)alloc((size_t)NF * 64 * 2);
  short* BT = (short*)alloc((size_t)4096 * 96 * 2);
  char* Yreg = w + off;
  size_t avail = (ws_size > off) ? (ws_size - off) : 0;
  size_t percell = (size_t)NF * 64 * 2;
  int CC = 64;
  while (CC > 8 && (size_t)CC * percell > avail) CC >>= 1;
  int S = 64 / CC;
  short* Y  = (short*)Yreg;
  float* Y4 = (float*)Yreg;

  hipMemsetAsync(fthist, 0, (size_t)NF * 8, stream);

  dual_hist<<<FBLK + BBLK, 256, 0, stream>>>(fi, bfi, fthist, bthist);
  csr_scan2<<<2, 1024, 0, stream>>>(fthist, bthist, ftstart, ftcur, btstart, btcur);
  dual_scatter<<<FBLK + BBLK, 256, 0, stream>>>(fi, bfi, ftcur, btcur, ftedges, btedges);
  dual_payload_basis<<<FBLK + BBLK, 256, 0, stream>>>(ftedges, btedges, fi, fj, bfi, bb,
                                                      fp, bp, sup, fpk, fwtP, bpk, bwtP);

  // Stage 1: fully fused, single pass. Emits ans0 + bf16 Xh96.
  b1_stage1<<<NF / 4, 256, 0, stream>>>(ff, bfe, fc0, W0, W1,
                                        ftstart, fpk, fwtP, btstart, bpk, bwtP,
                                        ans0, Xh96);
  // Stage 2: MFMA GEMM + gather. Emits ans1 + bf16 Xh64.
  buildBT<<<(4096 * 96 + 255) / 256, 256, 0, stream>>>(W2, BT, 96);
  for (int c = 0; c < S; c++) {
    int c0 = c * CC;
    gemm_bf16<96><<<dim3(NF / 128, CC * 64 / 128), 256, 0, stream>>>(
        Xh96, BT + (size_t)c0 * 64 * 96, Y, CC * 64);
    b23<96, 0, 1><<<NF / 4, 256, 0, stream>>>(ans0, fc1, ftstart, fpk, fwtP,
                                              Y, nullptr, ans1, Xh64,
                                              c0, CC, c == 0, c == S - 1);
  }
  // Stage 3
  buildBT<<<(4096 * 64 + 255) / 256, 256, 0, stream>>>(W3, BT, 64);
  for (int c = 0; c < S; c++) {
    int c0 = c * CC;
    gemm_bf16<64><<<dim3(NF / 128, CC * 64 / 128), 256, 0, stream>>>(
        Xh64, BT + (size_t)c0 * 64 * 64, Y, CC * 64);
    b23<64, 1, 0><<<NF / 4, 256, 0, stream>>>(ans1, fc2, ftstart, fpk, fwtP,
                                              Y, ans1, ans2, nullptr,
                                              c0, CC, c == 0, c == S - 1);
  }
  // Stage 4
  for (int c = 0; c < S; c++) {
    int c0 = c * CC;
    conv_k64_c2<<<NF / 4, 256, 0, stream>>>(ans2, W4, Y4, c0, CC);
    b4_stage4<<<NF / 4, 256, 0, stream>>>(ans2, fc3, ftstart, fpk, fwtP,
                                          Y4, outpre, out, c0, CC, c == 0, c == S - 1);
  }
}

// Round 9
// 435.837 us; speedup vs baseline: 7.2207x; 1.0665x over previous
//
#include <hip/hip_runtime.h>

#define NF 16384
#define NB 4096
#define EF 262144
#define EB 65536
#define FBLK 1024   // EF/256
#define BBLK 256    // EB/256

typedef __attribute__((ext_vector_type(8))) short bf16x8;
typedef __attribute__((ext_vector_type(4))) float f32x4;

__device__ __forceinline__ short f2b(float f) {
  unsigned u = __float_as_uint(f);
  u += 0x7fff + ((u >> 16) & 1);   // RNE
  return (short)(u >> 16);
}
__device__ __forceinline__ unsigned pack2(float lo, float hi) {
  return (unsigned)(unsigned short)f2b(lo) | ((unsigned)(unsigned short)f2b(hi) << 16);
}
__device__ __forceinline__ float b2f_lo(unsigned u) {
  return __uint_as_float(u << 16);
}
__device__ __forceinline__ float b2f_hi(unsigned u) {
  return __uint_as_float(u & 0xffff0000u);
}

// ---------------------------------------------------------------------------
// Target CSR build (fluid + boundary merged per launch).
// ---------------------------------------------------------------------------
__global__ void __launch_bounds__(256) dual_hist(const int* __restrict__ fi,
                                                 const int* __restrict__ bfi,
                                                 int* __restrict__ fhist,
                                                 int* __restrict__ bhist) {
  int bid = blockIdx.x;
  if (bid < FBLK) {
    int e = bid * 256 + threadIdx.x;
    atomicAdd(fhist + fi[e], 1);
  } else {
    int e = (bid - FBLK) * 256 + threadIdx.x;
    atomicAdd(bhist + bfi[e], 1);
  }
}

__global__ void __launch_bounds__(1024) csr_scan2(const int* __restrict__ fhist,
                                                  const int* __restrict__ bhist,
                                                  int* __restrict__ fstart, int* __restrict__ fcur,
                                                  int* __restrict__ bstart, int* __restrict__ bcur) {
  const int* hist = blockIdx.x ? bhist : fhist;
  int* start = blockIdx.x ? bstart : fstart;
  int* cursor = blockIdx.x ? bcur : fcur;
  __shared__ int wtot[16];
  int t = threadIdx.x;
  int lane = t & 63, wv = t >> 6;
  int base = t * 16;
  int vals[16];
  int s = 0;
#pragma unroll
  for (int k = 0; k < 16; k++) { vals[k] = hist[base + k]; s += vals[k]; }
  int ss = s;
  for (int off = 1; off < 64; off <<= 1) {
    int o = __shfl_up(ss, off, 64);
    if (lane >= off) ss += o;
  }
  if (lane == 63) wtot[wv] = ss;
  __syncthreads();
  if (t < 16) {
    int v = wtot[t];
    int vv = v;
    for (int off = 1; off < 16; off <<= 1) {
      int o = __shfl_up(vv, off, 64);
      if (t >= off) vv += o;
    }
    wtot[t] = vv - v;
  }
  __syncthreads();
  int run = ss - s + wtot[wv];
#pragma unroll
  for (int k = 0; k < 16; k++) { start[base + k] = run; cursor[base + k] = run; run += vals[k]; }
  if (t == 1023) start[16384] = run;
}

__global__ void __launch_bounds__(256) dual_scatter(const int* __restrict__ fi,
                                                    const int* __restrict__ bfi,
                                                    int* __restrict__ fcur, int* __restrict__ bcur,
                                                    int* __restrict__ fedges, int* __restrict__ bedges) {
  int bid = blockIdx.x;
  if (bid < FBLK) {
    int e = bid * 256 + threadIdx.x;
    int p = atomicAdd(fcur + fi[e], 1);
    fedges[p] = e;
  } else {
    int e = (bid - FBLK) * 256 + threadIdx.x;
    int p = atomicAdd(bcur + bfi[e], 1);
    bedges[p] = e;
  }
}

// ---------------------------------------------------------------------------
// Payload build WITH fused tent-basis math.
// ---------------------------------------------------------------------------
__global__ void __launch_bounds__(256) dual_payload_basis(
    const int* __restrict__ fedges, const int* __restrict__ bedges,
    const int* __restrict__ fi, const int* __restrict__ fj,
    const int* __restrict__ bfi, const int* __restrict__ bb,
    const float* __restrict__ fp, const float* __restrict__ bp,
    const float* __restrict__ supportp,
    unsigned* __restrict__ fpk, float4* __restrict__ fwt,
    unsigned* __restrict__ bpk, float4* __restrict__ bwt) {
  int bid = blockIdx.x;
  bool fluid = bid < FBLK;
  int idx = (fluid ? bid : bid - FBLK) * 256 + threadIdx.x;
  int e = fluid ? fedges[idx] : bedges[idx];
  int ti = fluid ? fi[e] : bfi[e];
  int si = fluid ? fj[e] : bb[e];
  const float2* pT2 = (const float2*)fp;
  const float2* pS2 = fluid ? (const float2*)fp : (const float2*)bp;
  float sign = fluid ? -1.f : 1.f;
  float inv_sup = 1.0f / supportp[0];
  float2 pt = pT2[ti];
  float2 ps = pS2[si];
  // d = sign*(src-tgt)/support. (-1)*(+0) = -0 preserves reference signed
  // zeros for self-edges (atan2(-0,-0) = -pi).
  float dx = sign * ((ps.x - pt.x) * inv_sup);
  float dy = sign * ((ps.y - pt.y) * inv_sup);
  dx = fminf(fmaxf(dx, -1.f), 1.f);
  dy = fminf(fmaxf(dy, -1.f), 1.f);
  float r = sqrtf(dx * dx + dy * dy + 1e-12f);
  float theta;
  if (dx == 0.0f && dy == 0.0f) {
    float mag = __builtin_signbitf(dx) ? 3.14159265358979323846f : 0.0f;
    theta = __builtin_signbitf(dy) ? -mag : mag;
  } else {
    theta = atan2f(dy, dx);
  }
  float u = 2.f * r - 1.f;
  float v = theta * (1.f / 3.14159265358979323846f);
  float tu = (u + 1.f) * 3.5f;
  float tv = (v + 1.f) * 3.5f;
  int iu = min(max((int)floorf(tu), 0), 6);
  int iv = min(max((int)floorf(tv), 0), 6);
  float wu0 = fmaxf(0.f, 1.f - fabsf(tu - (float)iu));
  float wu1 = fmaxf(0.f, 1.f - fabsf(tu - (float)(iu + 1)));
  float wv0 = fmaxf(0.f, 1.f - fabsf(tv - (float)iv));
  float wv1 = fmaxf(0.f, 1.f - fabsf(tv - (float)(iv + 1)));
  unsigned pk = (unsigned)si | ((unsigned)(iu * 8 + iv) << 14);
  float4 w4 = make_float4(wu0 * wv0, wu0 * wv1, wu1 * wv0, wu1 * wv1);
  if (fluid) { fpk[idx] = pk; fwt[idx] = w4; }
  else       { bpk[idx] = pk; bwt[idx] = w4; }
}

__global__ void __launch_bounds__(256) buildBT(const float* __restrict__ W,
                                               short* __restrict__ BT, int K) {
  int tid = blockIdx.x * 256 + threadIdx.x;
  if (tid >= 4096 * K) return;
  int k = tid % K, n = tid / K;
  BT[tid] = f2b(W[((size_t)(n >> 6) * K + k) * 64 + (n & 63)]);
}

// ---------------------------------------------------------------------------
// Dense MFMA GEMM (verified m89/m91 layout).
// ---------------------------------------------------------------------------
template <int K>
__global__ void __launch_bounds__(256, 2) gemm_bf16(
    const short* __restrict__ A, const short* __restrict__ BT,
    short* __restrict__ C, int N) {
  int lane = threadIdx.x & 63;
  int w = threadIdx.x >> 6;
  int m0 = blockIdx.x * 128 + (w & 1) * 64;
  int n0 = blockIdx.y * 128 + (w >> 1) * 64;
  int fr = lane & 15;
  int kg = lane >> 4;
  f32x4 acc[4][4] = {};
#pragma unroll
  for (int kc = 0; kc < K; kc += 32) {
    bf16x8 a[4], b[4];
#pragma unroll
    for (int i = 0; i < 4; i++) {
      a[i] = *(const bf16x8*)(A + (size_t)(m0 + i * 16 + fr) * K + kc + kg * 8);
      b[i] = *(const bf16x8*)(BT + (size_t)(n0 + i * 16 + fr) * K + kc + kg * 8);
    }
#pragma unroll
    for (int i = 0; i < 4; i++)
#pragma unroll
      for (int j = 0; j < 4; j++)
        acc[i][j] = __builtin_amdgcn_mfma_f32_16x16x32_bf16(a[i], b[j], acc[i][j], 0, 0, 0);
  }
#pragma unroll
  for (int i = 0; i < 4; i++) {
    int row = m0 + i * 16 + (lane >> 4) * 4;
#pragma unroll
    for (int j = 0; j < 4; j++) {
      int col = n0 + j * 16 + (lane & 15);
#pragma unroll
      for (int r = 0; r < 4; r++)
        C[(size_t)(row + r) * N + col] = f2b(acc[i][j][r]);
    }
  }
}

// ---------------------------------------------------------------------------
// Stage-4 dense conv (K=64, 2 couts/cell, fp32): wave per node, lane = cell.
// ---------------------------------------------------------------------------
__global__ void __launch_bounds__(256) conv_k64_c2(
    const float* __restrict__ x, const float* __restrict__ W4 /*[64][64][2]*/,
    float* __restrict__ Y4, int c0, int CC) {
  int lane = threadIdx.x & 63;
  int n = blockIdx.x * 4 + (threadIdx.x >> 6);
  float xv = x[(size_t)n * 64 + lane];
  int cell = c0 + lane;
  const float2* wr = (const float2*)(W4 + (size_t)cell * 128);
  float a0 = 0.f, a1 = 0.f;
#pragma unroll
  for (int k = 0; k < 64; k++) {
    float xk = __shfl(xv, k, 64);
    float2 wk = wr[k];
    a0 = fmaf(xk, wk.x, a0);
    a1 = fmaf(xk, wk.y, a1);
  }
  if (lane < CC)
    *(float2*)(Y4 + (size_t)n * (CC * 2) + lane * 2) = make_float2(a0, a1);
}

// ---------------------------------------------------------------------------
// Stage 1, fused; TWO waves per node (wave A: fluid conv -> cols 32..63,
// wave B: boundary conv -> 64..95 + lin -> 0..31). Node id readfirstlane'd so
// the whole idx->pk->wt->x chain is provably uniform => scalar s_load stream.
// ---------------------------------------------------------------------------
__global__ void __launch_bounds__(256, 4) b1_stage1(
    const float* __restrict__ ff, const float* __restrict__ bfe,
    const float* __restrict__ fc0,
    const float* __restrict__ W0, const float* __restrict__ W1,
    const int* __restrict__ ftstart, const unsigned* __restrict__ fpk,
    const float4* __restrict__ fwt,
    const int* __restrict__ btstart, const unsigned* __restrict__ bpk,
    const float4* __restrict__ bwt,
    float* __restrict__ ans0, short* __restrict__ Xh96) {
  int lane = threadIdx.x & 63;
  int wid = threadIdx.x >> 6;
  int t = __builtin_amdgcn_readfirstlane(blockIdx.x * 2 + (wid >> 1));
  int role = wid & 1;  // 0 = fluid, 1 = boundary+lin
  int q = lane >> 4;
  int p = lane & 15;
  int cofs = (q & 1) + (q >> 1) * 8;

  const unsigned* pkA = role ? bpk : fpk;
  const float4* wtA = role ? bwt : fwt;
  const int* stA = role ? btstart : ftstart;
  const float* xA = role ? bfe : ff;
  const float* WA = role ? W1 : W0;

  auto edge = [&](unsigned pk, float4 w4, float4 xv, float2& acc) {
    int cell = (int)(pk >> 14) + cofs;
    float wq = (q == 0) ? w4.x : (q == 1) ? w4.y : (q == 2) ? w4.z : w4.w;
    const float* Wc = WA + cell * 128 + 2 * p;
    float2 k0 = *(const float2*)(Wc);
    float2 k1 = *(const float2*)(Wc + 32);
    float2 k2 = *(const float2*)(Wc + 64);
    float2 k3 = *(const float2*)(Wc + 96);
    float m0 = xv.x * k0.x + xv.y * k1.x + xv.z * k2.x + xv.w * k3.x;
    float m1 = xv.x * k0.y + xv.y * k1.y + xv.z * k2.y + xv.w * k3.y;
    acc.x = fmaf(wq, m0, acc.x);
    acc.y = fmaf(wq, m1, acc.y);
  };

  float2 acc = make_float2(0.f, 0.f);
  int s = __builtin_amdgcn_readfirstlane(stA[t]);
  int e1 = __builtin_amdgcn_readfirstlane(stA[t + 1]);
  int idx = s;
  for (; idx + 3 < e1; idx += 4) {
    unsigned pk0 = pkA[idx], pk1 = pkA[idx + 1], pk2 = pkA[idx + 2], pk3 = pkA[idx + 3];
    float4 w0 = wtA[idx], w1 = wtA[idx + 1], w2 = wtA[idx + 2], w3 = wtA[idx + 3];
    float4 x0 = *(const float4*)(xA + (size_t)(pk0 & 16383) * 4);
    float4 x1 = *(const float4*)(xA + (size_t)(pk1 & 16383) * 4);
    float4 x2 = *(const float4*)(xA + (size_t)(pk2 & 16383) * 4);
    float4 x3 = *(const float4*)(xA + (size_t)(pk3 & 16383) * 4);
    edge(pk0, w0, x0, acc);
    edge(pk1, w1, x1, acc);
    edge(pk2, w2, x2, acc);
    edge(pk3, w3, x3, acc);
  }
  for (; idx < e1; idx++) {
    unsigned pk = pkA[idx];
    float4 w4 = wtA[idx];
    float4 xv = *(const float4*)(xA + (size_t)(pk & 16383) * 4);
    edge(pk, w4, xv, acc);
  }
  acc.x += __shfl_xor(acc.x, 16, 64); acc.y += __shfl_xor(acc.y, 16, 64);
  acc.x += __shfl_xor(acc.x, 32, 64); acc.y += __shfl_xor(acc.y, 32, 64);
  acc.x = fmaxf(acc.x, 0.f); acc.y = fmaxf(acc.y, 0.f);
  if (role == 0) {
    if (lane < 16) {
      *(float2*)(ans0 + (size_t)t * 96 + 32 + 2 * p) = acc;
      *(unsigned*)(Xh96 + (size_t)t * 96 + 32 + 2 * p) = pack2(acc.x, acc.y);
    }
  } else {
    if (lane < 16) {
      *(float2*)(ans0 + (size_t)t * 96 + 64 + 2 * p) = acc;
      *(unsigned*)(Xh96 + (size_t)t * 96 + 64 + 2 * p) = pack2(acc.x, acc.y);
    } else if (lane < 32) {
      float4 fv = *(const float4*)(ff + (size_t)t * 4);
      float l0 = fv.x * fc0[2 * p] + fv.y * fc0[32 + 2 * p] +
                 fv.z * fc0[64 + 2 * p] + fv.w * fc0[96 + 2 * p];
      float l1 = fv.x * fc0[2 * p + 1] + fv.y * fc0[32 + 2 * p + 1] +
                 fv.z * fc0[64 + 2 * p + 1] + fv.w * fc0[96 + 2 * p + 1];
      l0 = fmaxf(l0, 0.f); l1 = fmaxf(l1, 0.f);
      *(float2*)(ans0 + (size_t)t * 96 + 2 * p) = make_float2(l0, l1);
      *(unsigned*)(Xh96 + (size_t)t * 96 + 2 * p) = pack2(l0, l1);
    }
  }
}

// ---------------------------------------------------------------------------
// Phase B stages 2/3: quad-width Y gather + folded fc GEMM; 4-edge unroll.
// Payload stream scalarized (uniform node id via readfirstlane).
// ---------------------------------------------------------------------------
template <int CIN, int RESID, int WBF16>
__global__ void __launch_bounds__(256, 4) b23(
    const float* __restrict__ xin, const float* __restrict__ fc,
    const int* __restrict__ ftstart, const unsigned* __restrict__ epk,
    const float4* __restrict__ ewt, const short* __restrict__ Y,
    const float* __restrict__ resid, float* __restrict__ dest,
    short* __restrict__ Xh64, int c0, int CC, int init, int fin) {
  int lane = threadIdx.x & 63;
  int t = __builtin_amdgcn_readfirstlane(blockIdx.x * 4 + (threadIdx.x >> 6));
  int q = lane >> 4;
  int sub = lane & 15;
  int cofs = (q & 1) + (q >> 1) * 8;
  int YW = CC * 64;
  float a0 = 0.f, a1 = 0.f, a2 = 0.f, a3 = 0.f;
  if (init) {
    const float* xr = xin + (size_t)t * CIN;
#pragma unroll
    for (int kk = 0; kk < CIN / 4; kk++) {
      int k = q * (CIN / 4) + kk;
      float xv = xr[k];
      float4 fv = *(const float4*)(fc + (size_t)k * 64 + 4 * sub);
      a0 = fmaf(xv, fv.x, a0);
      a1 = fmaf(xv, fv.y, a1);
      a2 = fmaf(xv, fv.z, a2);
      a3 = fmaf(xv, fv.w, a3);
    }
  }
  int s = __builtin_amdgcn_readfirstlane(ftstart[t]);
  int e1 = __builtin_amdgcn_readfirstlane(ftstart[t + 1]);
  int idx = s;
  for (; idx + 3 < e1; idx += 4) {
    unsigned pk_[4];
    float4 w_[4];
    int cell_[4], src_[4];
    float wq_[4];
    uint2 r_[4];
#pragma unroll
    for (int j = 0; j < 4; j++) {
      pk_[j] = epk[idx + j];
      w_[j] = ewt[idx + j];
      src_[j] = pk_[j] & 16383;
      cell_[j] = (int)(pk_[j] >> 14) + cofs - c0;
      wq_[j] = (q == 0) ? w_[j].x : (q == 1) ? w_[j].y : (q == 2) ? w_[j].z : w_[j].w;
      r_[j] = make_uint2(0, 0);
      if ((unsigned)cell_[j] < (unsigned)CC)
        r_[j] = *(const uint2*)(Y + (size_t)src_[j] * YW + cell_[j] * 64 + 4 * sub);
    }
#pragma unroll
    for (int j = 0; j < 4; j++) {
      a0 = fmaf(wq_[j], b2f_lo(r_[j].x), a0);
      a1 = fmaf(wq_[j], b2f_hi(r_[j].x), a1);
      a2 = fmaf(wq_[j], b2f_lo(r_[j].y), a2);
      a3 = fmaf(wq_[j], b2f_hi(r_[j].y), a3);
    }
  }
  for (; idx < e1; idx++) {
    unsigned pk = epk[idx];
    float4 w4 = ewt[idx];
    int src = pk & 16383;
    int cell = (int)(pk >> 14) + cofs - c0;
    float wq = (q == 0) ? w4.x : (q == 1) ? w4.y : (q == 2) ? w4.z : w4.w;
    if ((unsigned)cell < (unsigned)CC) {
      uint2 r = *(const uint2*)(Y + (size_t)src * YW + cell * 64 + 4 * sub);
      a0 = fmaf(wq, b2f_lo(r.x), a0);
      a1 = fmaf(wq, b2f_hi(r.x), a1);
      a2 = fmaf(wq, b2f_lo(r.y), a2);
      a3 = fmaf(wq, b2f_hi(r.y), a3);
    }
  }
  a0 += __shfl_xor(a0, 16, 64); a1 += __shfl_xor(a1, 16, 64);
  a2 += __shfl_xor(a2, 16, 64); a3 += __shfl_xor(a3, 16, 64);
  a0 += __shfl_xor(a0, 32, 64); a1 += __shfl_xor(a1, 32, 64);
  a2 += __shfl_xor(a2, 32, 64); a3 += __shfl_xor(a3, 32, 64);
  if (lane < 16) {
    float4* dst = (float4*)(dest + (size_t)t * 64 + 4 * sub);
    if (!init) {
      float4 d = *dst;
      a0 += d.x; a1 += d.y; a2 += d.z; a3 += d.w;
    }
    if (RESID && init) {
      float4 rd = *(const float4*)(resid + (size_t)t * 64 + 4 * sub);
      a0 += rd.x; a1 += rd.y; a2 += rd.z; a3 += rd.w;
    }
    if (fin) {
      a0 = fmaxf(a0, 0.f); a1 = fmaxf(a1, 0.f);
      a2 = fmaxf(a2, 0.f); a3 = fmaxf(a3, 0.f);
    }
    *dst = make_float4(a0, a1, a2, a3);
    if (WBF16 && fin) {
      uint2 pkd = make_uint2(pack2(a0, a1), pack2(a2, a3));
      *(uint2*)(Xh64 + (size_t)t * 64 + 4 * sub) = pkd;
    }
  }
}

// ---------------------------------------------------------------------------
// Phase B stage 4: out[t] = gather(Y4) + ans2@fc3 (lane-parallel slots).
// ---------------------------------------------------------------------------
__global__ void __launch_bounds__(256, 4) b4_stage4(
    const float* __restrict__ ans2, const float* __restrict__ fc3,
    const int* __restrict__ ftstart, const unsigned* __restrict__ epk,
    const float4* __restrict__ ewt, const float* __restrict__ Y4,
    float* __restrict__ partial, float* __restrict__ outp,
    int c0, int CC, int init, int fin) {
  int lane = threadIdx.x & 63;
  int t = blockIdx.x * 4 + (threadIdx.x >> 6);
  int s4 = ftstart[t] * 4, e4 = ftstart[t + 1] * 4;
  float m0 = 0.f, m1 = 0.f;
  for (int fq = s4 + lane; fq < e4; fq += 64) {
    int idx = fq >> 2, j = fq & 3;
    unsigned pk = epk[idx];
    float4 w4 = ewt[idx];
    int src = pk & 16383;
    int cell = (int)(pk >> 14) + (j & 1) + (j >> 1) * 8 - c0;
    float w = (j == 0) ? w4.x : (j == 1) ? w4.y : (j == 2) ? w4.z : w4.w;
    if ((unsigned)cell < (unsigned)CC) {
      float2 mm = *(const float2*)(Y4 + (size_t)src * (CC * 2) + cell * 2);
      m0 += w * mm.x;
      m1 += w * mm.y;
    }
  }
  if (init) {
    float a = ans2[(size_t)t * 64 + lane];
    m0 += a * fc3[lane * 2 + 0];
    m1 += a * fc3[lane * 2 + 1];
  }
#pragma unroll
  for (int off = 32; off > 0; off >>= 1) {
    m0 += __shfl_xor(m0, off, 64);
    m1 += __shfl_xor(m1, off, 64);
  }
  if (lane == 0) {
    if (!init) { m0 += partial[t * 2]; m1 += partial[t * 2 + 1]; }
    if (fin) { outp[t * 2] = m0; outp[t * 2 + 1] = m1; }
    else { partial[t * 2] = m0; partial[t * 2 + 1] = m1; }
  }
}

// ---------------------------------------------------------------------------
extern "C" void kernel_launch(void* const* d_in, const int* in_sizes, int n_in,
                              void* d_out, int out_size, void* d_ws, size_t ws_size,
                              hipStream_t stream) {
  const float* fp  = (const float*)d_in[0];
  const float* bp  = (const float*)d_in[1];
  const float* ff  = (const float*)d_in[2];
  const float* bfe = (const float*)d_in[3];
  const float* sup = (const float*)d_in[4];
  const int* fi  = (const int*)d_in[5];
  const int* fj  = (const int*)d_in[6];
  const int* bfi = (const int*)d_in[7];
  const int* bb  = (const int*)d_in[8];
  const float* W0 = (const float*)d_in[9];
  const float* W1 = (const float*)d_in[10];
  const float* W2 = (const float*)d_in[11];
  const float* W3 = (const float*)d_in[12];
  const float* W4 = (const float*)d_in[13];
  const float* fc0 = (const float*)d_in[14];
  const float* fc1 = (const float*)d_in[15];
  const float* fc2 = (const float*)d_in[16];
  const float* fc3 = (const float*)d_in[17];
  float* out = (float*)d_out;

  char* w = (char*)d_ws;
  size_t off = 0;
  auto alloc = [&](size_t bytes) {
    char* p = w + off;
    off += (bytes + 255) & ~size_t(255);
    return p;
  };
  float* ans0   = (float*)alloc((size_t)NF * 96 * 4);
  float* ans1   = (float*)alloc((size_t)NF * 64 * 4);
  float* ans2   = (float*)alloc((size_t)NF * 64 * 4);
  float* outpre = (float*)alloc((size_t)NF * 2 * 4);
  int* fthist  = (int*)alloc((size_t)NF * 4);
  int* bthist  = (int*)alloc((size_t)NF * 4);   // adjacent to fthist: one memset
  int* ftstart = (int*)alloc((size_t)(NF + 1) * 4);
  int* ftcur   = (int*)alloc((size_t)NF * 4);
  int* ftedges = (int*)alloc((size_t)EF * 4);
  int* btstart = (int*)alloc((size_t)(NF + 1) * 4);
  int* btcur   = (int*)alloc((size_t)NF * 4);
  int* btedges = (int*)alloc((size_t)EB * 4);
  unsigned* fpk  = (unsigned*)alloc((size_t)EF * 4);
  float4* fwtP   = (float4*)alloc((size_t)EF * 16);
  unsigned* bpk  = (unsigned*)alloc((size_t)EB * 4);
  float4* bwtP   = (float4*)alloc((size_t)EB * 16);
  short* Xh96 = (short*)alloc((size_t)NF * 96 * 2);
  short* Xh64 = (short*)alloc((size_t)NF * 64 * 2);
  short* BT = (short*)alloc((size_t)4096 * 96 * 2);
  char* Yreg = w + off;
  size_t avail = (ws_size > off) ? (ws_size - off) : 0;
  size_t percell = (size_t)NF * 64 * 2;
  int CC = 64;
  while (CC > 8 && (size_t)CC * percell > avail) CC >>= 1;
  int S = 64 / CC;
  short* Y  = (short*)Yreg;
  float* Y4 = (float*)Yreg;

  hipMemsetAsync(fthist, 0, (size_t)NF * 8, stream);

  dual_hist<<<FBLK + BBLK, 256, 0, stream>>>(fi, bfi, fthist, bthist);
  csr_scan2<<<2, 1024, 0, stream>>>(fthist, bthist, ftstart, ftcur, btstart, btcur);
  dual_scatter<<<FBLK + BBLK, 256, 0, stream>>>(fi, bfi, ftcur, btcur, ftedges, btedges);
  dual_payload_basis<<<FBLK + BBLK, 256, 0, stream>>>(ftedges, btedges, fi, fj, bfi, bb,
                                                      fp, bp, sup, fpk, fwtP, bpk, bwtP);

  // Stage 1: fused, 2 waves/node. Emits ans0 + bf16 Xh96.
  b1_stage1<<<NF / 2, 256, 0, stream>>>(ff, bfe, fc0, W0, W1,
                                        ftstart, fpk, fwtP, btstart, bpk, bwtP,
                                        ans0, Xh96);
  // Stage 2: MFMA GEMM + gather. Emits ans1 + bf16 Xh64.
  buildBT<<<(4096 * 96 + 255) / 256, 256, 0, stream>>>(W2, BT, 96);
  for (int c = 0; c < S; c++) {
    int c0 = c * CC;
    gemm_bf16<96><<<dim3(NF / 128, CC * 64 / 128), 256, 0, stream>>>(
        Xh96, BT + (size_t)c0 * 64 * 96, Y, CC * 64);
    b23<96, 0, 1><<<NF / 4, 256, 0, stream>>>(ans0, fc1, ftstart, fpk, fwtP,
                                              Y, nullptr, ans1, Xh64,
                                              c0, CC, c == 0, c == S - 1);
  }
  // Stage 3
  buildBT<<<(4096 * 64 + 255) / 256, 256, 0, stream>>>(W3, BT, 64);
  for (int c = 0; c < S; c++) {
    int c0 = c * CC;
    gemm_bf16<64><<<dim3(NF / 128, CC * 64 / 128), 256, 0, stream>>>(
        Xh64, BT + (size_t)c0 * 64 * 64, Y, CC * 64);
    b23<64, 1, 0><<<NF / 4, 256, 0, stream>>>(ans1, fc2, ftstart, fpk, fwtP,
                                              Y, ans1, ans2, nullptr,
                                              c0, CC, c == 0, c == S - 1);
  }
  // Stage 4
  for (int c = 0; c < S; c++) {
    int c0 = c * CC;
    conv_k64_c2<<<NF / 4, 256, 0, stream>>>(ans2, W4, Y4, c0, CC);
    b4_stage4<<<NF / 4, 256, 0, stream>>>(ans2, fc3, ftstart, fpk, fwtP,
                                          Y4, outpre, out, c0, CC, c == 0, c == S - 1);
  }
}